// Round 6
// baseline (5969.181 us; speedup 1.0000x reference)
//
#include <hip/hip_runtime.h>
#include <stdint.h>

typedef __bf16 bf16x8 __attribute__((ext_vector_type(8)));
typedef float f32x4 __attribute__((ext_vector_type(4)));

#define DEV __device__ __forceinline__

constexpr int SEQ = 2048;
constexpr int DIM = 2048;
constexpr int NH  = 16;
constexpr int DK  = 128;
constexpr int BATCH = 2;
constexpr size_t TSZ = (size_t)BATCH * SEQ * DIM;   // 8388608 elements
constexpr size_t WSZ = (size_t)DIM * DIM;           // 4194304 elements per weight
constexpr float ATTN_SCALE = 0.08838834764831845f;  // 1/sqrt(128)

DEV unsigned short f2bf(float f) {
  unsigned int u = __float_as_uint(f);
  unsigned int r = (u + 0x7fffu + ((u >> 16) & 1u)) >> 16;
  return (unsigned short)r;
}

DEV float bf2f(unsigned short s) {
  unsigned int u = ((unsigned int)s) << 16;
  return __uint_as_float(u);
}

// ---------------------------------------------------------------------------
// fp32 -> bf16 (RTNE), 8 elements/thread, vectorized.
// ---------------------------------------------------------------------------
__global__ __launch_bounds__(256)
void cvt_f32_bf16(const float* __restrict__ src, unsigned short* __restrict__ dst,
                  int n8) {
  int i = blockIdx.x * 256 + threadIdx.x;
  if (i >= n8) return;
  float4 a = *reinterpret_cast<const float4*>(src + (size_t)i * 8);
  float4 b = *reinterpret_cast<const float4*>(src + (size_t)i * 8 + 4);
  unsigned short o[8];
  o[0] = f2bf(a.x); o[1] = f2bf(a.y); o[2] = f2bf(a.z); o[3] = f2bf(a.w);
  o[4] = f2bf(b.x); o[5] = f2bf(b.y); o[6] = f2bf(b.z); o[7] = f2bf(b.w);
  *reinterpret_cast<uint4*>(dst + (size_t)i * 8) = *reinterpret_cast<const uint4*>(o);
}

// ---------------------------------------------------------------------------
// GEMM: C[M,Nc] = A[M,K] * W[Nc,K]^T   (row-major, bf16 in, fp32 acc)
// 128x128 tile, BK=64, 4 waves (2x2), XOR-swizzled LDS, reg-staged prefetch.
// F32OUT=0: bf16 store to Db.  F32OUT=1: f32 store to Df.
// ---------------------------------------------------------------------------
template <int F32OUT>
__global__ __launch_bounds__(256, 2)
void gemm_bt(const unsigned short* __restrict__ A,
             const unsigned short* __restrict__ W,
             unsigned short* __restrict__ Db,
             float* __restrict__ Df) {
  __shared__ __align__(16) unsigned short As[128 * 64];
  __shared__ __align__(16) unsigned short Bs[128 * 64];

  const int t = threadIdx.x;
  const int lane = t & 63;
  const int wid = t >> 6;
  const int wr = (wid >> 1) << 6;   // 0 / 64
  const int wc = (wid & 1) << 6;
  const int l16 = lane & 15, lg = lane >> 4;
  const int row0 = blockIdx.y * 128;
  const int col0 = blockIdx.x * 128;

  const int srow = t >> 3;          // 0..31
  const int scol = t & 7;           // 16B chunk within 64-elem row
  const unsigned short* Arow = A + (size_t)(row0 + srow) * DIM + (scol << 3);
  const unsigned short* Wrow = W + (size_t)(col0 + srow) * DIM + (scol << 3);

  f32x4 acc[4][4] = {};

  uint4 pa[4], pb[4];
#pragma unroll
  for (int s = 0; s < 4; ++s) {
    pa[s] = *reinterpret_cast<const uint4*>(Arow + (size_t)s * 32 * DIM);
    pb[s] = *reinterpret_cast<const uint4*>(Wrow + (size_t)s * 32 * DIM);
  }

  for (int k0 = 0; k0 < DIM; k0 += 64) {
    __syncthreads();
#pragma unroll
    for (int s = 0; s < 4; ++s) {
      int r = s * 32 + srow;
      int sw = (scol ^ (r & 7)) << 3;
      *reinterpret_cast<uint4*>(&As[r * 64 + sw]) = pa[s];
      *reinterpret_cast<uint4*>(&Bs[r * 64 + sw]) = pb[s];
    }
    __syncthreads();
    if (k0 + 64 < DIM) {
#pragma unroll
      for (int s = 0; s < 4; ++s) {
        pa[s] = *reinterpret_cast<const uint4*>(Arow + (k0 + 64) + (size_t)s * 32 * DIM);
        pb[s] = *reinterpret_cast<const uint4*>(Wrow + (k0 + 64) + (size_t)s * 32 * DIM);
      }
    }
#pragma unroll
    for (int ks = 0; ks < 2; ++ks) {
      bf16x8 af[4], bfr[4];
#pragma unroll
      for (int i = 0; i < 4; ++i) {
        int ra = wr + i * 16 + l16;
        af[i] = *reinterpret_cast<const bf16x8*>(&As[ra * 64 + (((ks * 4 + lg) ^ (ra & 7)) << 3)]);
        int rb = wc + i * 16 + l16;
        bfr[i] = *reinterpret_cast<const bf16x8*>(&Bs[rb * 64 + (((ks * 4 + lg) ^ (rb & 7)) << 3)]);
      }
#pragma unroll
      for (int i = 0; i < 4; ++i)
#pragma unroll
        for (int j = 0; j < 4; ++j)
          acc[i][j] = __builtin_amdgcn_mfma_f32_16x16x32_bf16(af[i], bfr[j], acc[i][j], 0, 0, 0);
    }
  }

#pragma unroll
  for (int i = 0; i < 4; ++i)
#pragma unroll
    for (int j = 0; j < 4; ++j) {
      int colg = col0 + wc + j * 16 + l16;
#pragma unroll
      for (int r = 0; r < 4; ++r) {
        int rowg = row0 + wr + i * 16 + lg * 4 + r;
        if (F32OUT)
          Df[(size_t)rowg * DIM + colg] = acc[i][j][r];
        else
          Db[(size_t)rowg * DIM + colg] = f2bf(acc[i][j][r]);
      }
    }
}

// ---------------------------------------------------------------------------
// RoPE + scatter: P [B*S, DIM] bf16 row-major  ->  D [B,H,S,DK] float32.
// One thread per (even,odd) pair. Accurate sincosf/expf.  ROPE=0: scatter only.
// ---------------------------------------------------------------------------
template <int ROPE>
__global__ __launch_bounds__(256)
void rope_scatter(const unsigned short* __restrict__ P,
                  float* __restrict__ D) {
  size_t pi = (size_t)blockIdx.x * 256 + threadIdx.x;  // pair index < TSZ/2
  int row = (int)(pi >> 10);        // row in [0, B*S)
  int cp  = (int)(pi & 1023);       // pair within row (DIM/2 = 1024)
  int h = cp >> 6;                  // 64 pairs per head
  int j = cp & 63;                  // pair index within head
  int b = row >> 11, pos = row & (SEQ - 1);

  float x1 = bf2f(P[((size_t)row << 11) + 2 * cp]);
  float x2 = bf2f(P[((size_t)row << 11) + 2 * cp + 1]);
  float o1, o2;
  if (ROPE) {
    float inv = expf((float)j * -0.14391156831212787f);  // 10000^(-j/64)
    float ang = (float)pos * inv;
    float sn, cs;
    sincosf(ang, &sn, &cs);
    o1 = x1 * cs - x2 * sn;
    o2 = x1 * sn + x2 * cs;
  } else {
    o1 = x1; o2 = x2;
  }
  size_t idx = ((((size_t)(b * NH + h)) * SEQ + pos) << 7) + 2 * j;
  *reinterpret_cast<float2*>(&D[idx]) = make_float2(o1, o2);
}

// ---------------------------------------------------------------------------
// NAIVE causal attention: one block per (q, b*h), 128 threads.
// Q,K,V in [B,H,S,DK] float32.  AO [B*S, DIM] bf16 (head-concat columns).
// ---------------------------------------------------------------------------
__global__ __launch_bounds__(128)
void attn_naive(const float* __restrict__ Q,
                const float* __restrict__ K,
                const float* __restrict__ V,
                unsigned short* __restrict__ AO) {
  __shared__ float qv[DK];
  __shared__ float sc[SEQ];
  __shared__ float red[128];

  const int q  = blockIdx.x;
  const int bh = blockIdx.y;
  const int b  = bh >> 4, h = bh & 15;
  const int t  = threadIdx.x;
  const int nk = q + 1;

  qv[t] = Q[((size_t)bh * SEQ + q) * DK + t];
  __syncthreads();

  for (int k = t; k < nk; k += 128) {
    const float* Kr = K + ((size_t)bh * SEQ + k) * DK;
    float s = 0.f;
#pragma unroll 8
    for (int d = 0; d < DK; ++d) s += qv[d] * Kr[d];
    sc[k] = s * ATTN_SCALE;
  }
  __syncthreads();

  float lm = -INFINITY;
  for (int k = t; k < nk; k += 128) lm = fmaxf(lm, sc[k]);
  red[t] = lm;
  __syncthreads();
  if (t == 0) {
    float m = red[0];
    for (int i = 1; i < 128; ++i) m = fmaxf(m, red[i]);
    red[0] = m;
  }
  __syncthreads();
  const float m = red[0];
  __syncthreads();

  float ls = 0.f;
  for (int k = t; k < nk; k += 128) {
    float p = __expf(sc[k] - m);
    sc[k] = p;
    ls += p;
  }
  red[t] = ls;
  __syncthreads();
  if (t == 0) {
    float s = 0.f;
    for (int i = 0; i < 128; ++i) s += red[i];
    red[0] = s;
  }
  __syncthreads();
  const float inv = 1.0f / red[0];

  float o = 0.f;
  for (int k = 0; k < nk; ++k)
    o += sc[k] * V[((size_t)bh * SEQ + k) * DK + t];

  AO[((size_t)(b * SEQ + q)) * DIM + h * DK + t] = f2bf(o * inv);
}

// ---------------------------------------------------------------------------
extern "C" void kernel_launch(void* const* d_in, const int* in_sizes, int n_in,
                              void* d_out, int out_size, void* d_ws, size_t ws_size,
                              hipStream_t stream) {
  const float* x  = (const float*)d_in[0];
  const float* wq = (const float*)d_in[1];
  const float* wk = (const float*)d_in[2];
  const float* wv = (const float*)d_in[3];
  const float* wo = (const float*)d_in[4];

  // Outputs are FLOAT32 (reference returns f32): out, K, V concatenated.
  float* outF = (float*)d_out;
  float* outQ = outF;            // scratch: roped Q f32, dead before final GEMM
  float* outK = outF + TSZ;      // [B,H,S,DK] roped K (output 1)
  float* outV = outF + 2 * TSZ;  // [B,H,S,DK] V      (output 2)

  // ws (bf16 elems), total 2*TSZ + WSZ = 41.9 MB:
  unsigned short* xb  = (unsigned short*)d_ws;  // converted x
  unsigned short* aop = xb + TSZ;               // projection staging / AO
  unsigned short* wb  = xb + 2 * TSZ;           // jit-converted weight

  dim3 blk(256);
  dim3 ggrid(16, 32);
  const int cvtW = (int)(WSZ / 2048), n8W = (int)(WSZ / 8);
  const int scGrid = (int)(TSZ / 2 / 256);

  cvt_f32_bf16<<<dim3((int)(TSZ / 2048)), blk, 0, stream>>>(x, xb, (int)(TSZ / 8));

  cvt_f32_bf16<<<dim3(cvtW), blk, 0, stream>>>(wq, wb, n8W);
  gemm_bt<0><<<ggrid, blk, 0, stream>>>(xb, wb, aop, nullptr);
  rope_scatter<1><<<dim3(scGrid), blk, 0, stream>>>(aop, outQ);

  cvt_f32_bf16<<<dim3(cvtW), blk, 0, stream>>>(wk, wb, n8W);
  gemm_bt<0><<<ggrid, blk, 0, stream>>>(xb, wb, aop, nullptr);
  rope_scatter<1><<<dim3(scGrid), blk, 0, stream>>>(aop, outK);

  cvt_f32_bf16<<<dim3(cvtW), blk, 0, stream>>>(wv, wb, n8W);
  gemm_bt<0><<<ggrid, blk, 0, stream>>>(xb, wb, aop, nullptr);
  rope_scatter<0><<<dim3(scGrid), blk, 0, stream>>>(aop, outV);

  attn_naive<<<dim3(SEQ, 32), dim3(128), 0, stream>>>(outQ, outK, outV, aop);

  cvt_f32_bf16<<<dim3(cvtW), blk, 0, stream>>>(wo, wb, n8W);
  gemm_bt<1><<<ggrid, blk, 0, stream>>>(aop, wb, nullptr, outF);
}

// Round 7
// 911.879 us; speedup vs baseline: 6.5460x; 6.5460x over previous
//
#include <hip/hip_runtime.h>
#include <stdint.h>

typedef __bf16 bf16x8 __attribute__((ext_vector_type(8)));
typedef float f32x4 __attribute__((ext_vector_type(4)));

#define DEV __device__ __forceinline__

constexpr int SEQ = 2048;
constexpr int DIM = 2048;
constexpr int NH  = 16;
constexpr int DK  = 128;
constexpr int BATCH = 2;
constexpr size_t TSZ = (size_t)BATCH * SEQ * DIM;   // 8388608 elements
constexpr size_t WSZ = (size_t)DIM * DIM;           // 4194304 elements per weight
constexpr float ATTN_SCALE = 0.08838834764831845f;  // 1/sqrt(128)

DEV unsigned short f2bf(float f) {
  unsigned int u = __float_as_uint(f);
  unsigned int r = (u + 0x7fffu + ((u >> 16) & 1u)) >> 16;
  return (unsigned short)r;
}

DEV float bf2f(unsigned short s) {
  unsigned int u = ((unsigned int)s) << 16;
  return __uint_as_float(u);
}

// ---------------------------------------------------------------------------
// fp32 -> bf16 (RTNE), 8 elements/thread, vectorized.
// ---------------------------------------------------------------------------
__global__ __launch_bounds__(256)
void cvt_f32_bf16(const float* __restrict__ src, unsigned short* __restrict__ dst,
                  int n8) {
  int i = blockIdx.x * 256 + threadIdx.x;
  if (i >= n8) return;
  float4 a = *reinterpret_cast<const float4*>(src + (size_t)i * 8);
  float4 b = *reinterpret_cast<const float4*>(src + (size_t)i * 8 + 4);
  unsigned short o[8];
  o[0] = f2bf(a.x); o[1] = f2bf(a.y); o[2] = f2bf(a.z); o[3] = f2bf(a.w);
  o[4] = f2bf(b.x); o[5] = f2bf(b.y); o[6] = f2bf(b.z); o[7] = f2bf(b.w);
  *reinterpret_cast<uint4*>(dst + (size_t)i * 8) = *reinterpret_cast<const uint4*>(o);
}

// ---------------------------------------------------------------------------
// GEMM: C[M,Nc] = A[M,K] * W[Nc,K]^T   (row-major, bf16 in, fp32 acc)
// 128x128 tile, BK=64, 4 waves (2x2), XOR-swizzled LDS, reg-staged prefetch.
// MODE 0: plain row-major f32 store to Df            (WO projection)
// MODE 1: RoPE -> scatter [B,H,S,DK] bf16 to Db      (Q)
// MODE 2: RoPE -> scatter f32 to Df AND bf16 to Db   (K)
// MODE 3: scatter f32 to Df                          (V)
// ---------------------------------------------------------------------------
template <int MODE>
__global__ __launch_bounds__(256, 2)
void gemm_rope(const unsigned short* __restrict__ A,
               const unsigned short* __restrict__ W,
               unsigned short* __restrict__ Db,
               float* __restrict__ Df) {
  __shared__ __align__(16) unsigned short As[128 * 64];
  __shared__ __align__(16) unsigned short Bs[128 * 64];

  const int t = threadIdx.x;
  const int lane = t & 63;
  const int wid = t >> 6;
  const int wr = (wid >> 1) << 6;   // 0 / 64
  const int wc = (wid & 1) << 6;
  const int l16 = lane & 15, lg = lane >> 4;
  const int row0 = blockIdx.y * 128;
  const int col0 = blockIdx.x * 128;

  const int srow = t >> 3;          // 0..31
  const int scol = t & 7;           // 16B chunk within 64-elem row
  const unsigned short* Arow = A + (size_t)(row0 + srow) * DIM + (scol << 3);
  const unsigned short* Wrow = W + (size_t)(col0 + srow) * DIM + (scol << 3);

  f32x4 acc[4][4] = {};

  uint4 pa[4], pb[4];
#pragma unroll
  for (int s = 0; s < 4; ++s) {
    pa[s] = *reinterpret_cast<const uint4*>(Arow + (size_t)s * 32 * DIM);
    pb[s] = *reinterpret_cast<const uint4*>(Wrow + (size_t)s * 32 * DIM);
  }

  for (int k0 = 0; k0 < DIM; k0 += 64) {
    __syncthreads();
#pragma unroll
    for (int s = 0; s < 4; ++s) {
      int r = s * 32 + srow;
      int sw = (scol ^ (r & 7)) << 3;
      *reinterpret_cast<uint4*>(&As[r * 64 + sw]) = pa[s];
      *reinterpret_cast<uint4*>(&Bs[r * 64 + sw]) = pb[s];
    }
    __syncthreads();
    if (k0 + 64 < DIM) {
#pragma unroll
      for (int s = 0; s < 4; ++s) {
        pa[s] = *reinterpret_cast<const uint4*>(Arow + (k0 + 64) + (size_t)s * 32 * DIM);
        pb[s] = *reinterpret_cast<const uint4*>(Wrow + (k0 + 64) + (size_t)s * 32 * DIM);
      }
    }
#pragma unroll
    for (int ks = 0; ks < 2; ++ks) {
      bf16x8 af[4], bfr[4];
#pragma unroll
      for (int i = 0; i < 4; ++i) {
        int ra = wr + i * 16 + l16;
        af[i] = *reinterpret_cast<const bf16x8*>(&As[ra * 64 + (((ks * 4 + lg) ^ (ra & 7)) << 3)]);
        int rb = wc + i * 16 + l16;
        bfr[i] = *reinterpret_cast<const bf16x8*>(&Bs[rb * 64 + (((ks * 4 + lg) ^ (rb & 7)) << 3)]);
      }
#pragma unroll
      for (int i = 0; i < 4; ++i)
#pragma unroll
        for (int j = 0; j < 4; ++j)
          acc[i][j] = __builtin_amdgcn_mfma_f32_16x16x32_bf16(af[i], bfr[j], acc[i][j], 0, 0, 0);
    }
  }

  if (MODE == 0) {
#pragma unroll
    for (int i = 0; i < 4; ++i)
#pragma unroll
      for (int j = 0; j < 4; ++j) {
        int colg = col0 + wc + j * 16 + l16;
#pragma unroll
        for (int r = 0; r < 4; ++r) {
          int rowg = row0 + wr + i * 16 + lg * 4 + r;
          Df[(size_t)rowg * DIM + colg] = acc[i][j][r];
        }
      }
  } else {
#pragma unroll
    for (int j = 0; j < 4; ++j) {
      int colg = col0 + wc + j * 16 + l16;
      int jj = (colg >> 1) & 63;
      float invf = __expf((float)jj * -0.14391156831212787f);  // 10000^(-jj/64)
#pragma unroll
      for (int i = 0; i < 4; ++i) {
#pragma unroll
        for (int r = 0; r < 4; ++r) {
          int rowg = row0 + wr + i * 16 + lg * 4 + r;
          float v = acc[i][j][r];
          float outv;
          if (MODE == 1 || MODE == 2) {
            float p = __shfl_xor(v, 1, 64);
            int pos = rowg & (SEQ - 1);
            float ang = (float)pos * invf;
            float sn, cs;
            __sincosf(ang, &sn, &cs);
            // even col: x1*c - x2*s ; odd col: x1*s + x2*c
            outv = (colg & 1) ? fmaf(p, sn, v * cs) : fmaf(v, cs, -(p * sn));
          } else {
            outv = v;
          }
          int b = rowg >> 11, pos = rowg & (SEQ - 1);
          int h = colg >> 7, d = colg & (DK - 1);
          size_t idx = (((size_t)(b * NH + h)) * SEQ + pos) * DK + d;
          if (MODE == 1) Db[idx] = f2bf(outv);
          if (MODE == 2) { Df[idx] = outv; Db[idx] = f2bf(outv); }
          if (MODE == 3) Df[idx] = outv;
        }
      }
    }
  }
}

// ---------------------------------------------------------------------------
// V^T builder: V [B,H,S,DK] f32 -> VT [B,H,DK,S] bf16
// ---------------------------------------------------------------------------
__global__ __launch_bounds__(256, 2)
void vtrans(const float* __restrict__ V, unsigned short* __restrict__ VT) {
  __shared__ float vs[64 * 128];  // 32KB [pos][d]
  const int t = threadIdx.x;
  const int bh = blockIdx.y;
  const int p0 = blockIdx.x * 64;
  const float* src = V + ((size_t)bh * SEQ + p0) * DK;
#pragma unroll
  for (int s = 0; s < 8; ++s) {
    int id = s * 256 + t;
    *reinterpret_cast<float4*>(&vs[id * 4]) = *reinterpret_cast<const float4*>(&src[id * 4]);
  }
  __syncthreads();
  const int w = t >> 6, l = t & 63;
  unsigned short* dstb = VT + (size_t)bh * DK * SEQ + p0;
#pragma unroll
  for (int it = 0; it < 4; ++it) {
    int d = w * 32 + (it & 1) * 16 + (l & 15);
    int kc = (it >> 1) * 4 + (l >> 4);
    unsigned short tmp[8];
#pragma unroll
    for (int j = 0; j < 8; ++j) tmp[j] = f2bf(vs[(kc * 8 + j) * DK + d]);
    *reinterpret_cast<uint4*>(&dstb[(size_t)d * SEQ + kc * 8]) =
        *reinterpret_cast<const uint4*>(tmp);
  }
}

// ---------------------------------------------------------------------------
// Fused causal flash attention.  Q [B,H,S,DK] bf16 (roped), K same, VT
// [B,H,DK,S] bf16 -> AO [B*S, DIM] bf16 (head-concat, ready for WO gemm).
// Block: 256 thr / 4 waves; Q-tile 128 (32 rows/wave); KV-tile 64.
// ---------------------------------------------------------------------------
struct __align__(16) AttnSmem {
  unsigned short Qs[128 * 128];   // 32KB  [q][dk], swizzled
  unsigned short Ks[64 * 128];    // 16KB  [key][dk], swizzled
  unsigned short Vts[128 * 64];   // 16KB  [d][key], swizzled
  unsigned short Ps[4 * 32 * 64]; // 16KB  per-wave P [q][key], swizzled
};

__global__ __launch_bounds__(256, 2)
void attn_fused(const unsigned short* __restrict__ Q,
                const unsigned short* __restrict__ K,
                const unsigned short* __restrict__ VT,
                unsigned short* __restrict__ AO) {
  __shared__ AttnSmem sm;
  const int t = threadIdx.x;
  const int lane = t & 63;
  const int wid = t >> 6;
  const int l16 = lane & 15, lg = lane >> 4;
  const int qt = (int)(gridDim.x - 1 - blockIdx.x);  // heavy tiles first
  const int bh = blockIdx.y;
  const int b = bh >> 4, h = bh & 15;
  const int q0 = qt * 128;

  const unsigned short* Qbase = Q + ((size_t)bh * SEQ + q0) * DK;
  const unsigned short* Kbase = K + (size_t)bh * SEQ * DK;
  const unsigned short* VTbase = VT + (size_t)bh * DK * SEQ;

  // stage Q tile [128][128]: 256B rows -> 16 chunks, swizzle c^(r&7)
#pragma unroll
  for (int s = 0; s < 8; ++s) {
    int id = s * 256 + t;
    int r = id >> 4, c = id & 15;
    uint4 v = *reinterpret_cast<const uint4*>(Qbase + (size_t)r * DK + (c << 3));
    *reinterpret_cast<uint4*>(&sm.Qs[r * 128 + ((c ^ (r & 7)) << 3)]) = v;
  }

  f32x4 accO[2][8] = {};
  float mrun[2][4], lrun[2][4];
#pragma unroll
  for (int mi = 0; mi < 2; ++mi)
#pragma unroll
    for (int r = 0; r < 4; ++r) { mrun[mi][r] = -INFINITY; lrun[mi][r] = 0.f; }

  const int nkv = (q0 + 128) / 64;

  uint4 pk[4], pv[4];
#pragma unroll
  for (int s = 0; s < 4; ++s) {
    int id = s * 256 + t;
    int rk = id >> 4, ck = id & 15;
    pk[s] = *reinterpret_cast<const uint4*>(Kbase + (size_t)rk * DK + (ck << 3));
    int rv = id >> 3, cv = id & 7;
    pv[s] = *reinterpret_cast<const uint4*>(VTbase + (size_t)rv * SEQ + (cv << 3));
  }

  for (int kt = 0; kt < nkv; ++kt) {
    const int key0 = kt * 64;
    __syncthreads();
#pragma unroll
    for (int s = 0; s < 4; ++s) {
      int id = s * 256 + t;
      int rk = id >> 4, ck = id & 15;
      *reinterpret_cast<uint4*>(&sm.Ks[rk * 128 + ((ck ^ (rk & 7)) << 3)]) = pk[s];
      int rv = id >> 3, cv = id & 7;
      *reinterpret_cast<uint4*>(&sm.Vts[rv * 64 + ((cv ^ (rv & 7)) << 3)]) = pv[s];
    }
    __syncthreads();
    if (kt + 1 < nkv) {
      const int kn = key0 + 64;
#pragma unroll
      for (int s = 0; s < 4; ++s) {
        int id = s * 256 + t;
        int rk = id >> 4, ck = id & 15;
        pk[s] = *reinterpret_cast<const uint4*>(Kbase + (size_t)(kn + rk) * DK + (ck << 3));
        int rv = id >> 3, cv = id & 7;
        pv[s] = *reinterpret_cast<const uint4*>(VTbase + (size_t)rv * SEQ + kn + (cv << 3));
      }
    }

    // ---- S = Q K^T -------------------------------------------------------
    f32x4 sf[2][4] = {};
#pragma unroll
    for (int ks = 0; ks < 4; ++ks) {
      bf16x8 aq[2], bk[4];
#pragma unroll
      for (int mi = 0; mi < 2; ++mi) {
        int r = wid * 32 + mi * 16 + l16;
        aq[mi] = *reinterpret_cast<const bf16x8*>(
            &sm.Qs[r * 128 + (((ks * 4 + lg) ^ (r & 7)) << 3)]);
      }
#pragma unroll
      for (int nj = 0; nj < 4; ++nj) {
        int r = nj * 16 + l16;
        bk[nj] = *reinterpret_cast<const bf16x8*>(
            &sm.Ks[r * 128 + (((ks * 4 + lg) ^ (r & 7)) << 3)]);
      }
#pragma unroll
      for (int mi = 0; mi < 2; ++mi)
#pragma unroll
        for (int nj = 0; nj < 4; ++nj)
          sf[mi][nj] = __builtin_amdgcn_mfma_f32_16x16x32_bf16(aq[mi], bk[nj], sf[mi][nj], 0, 0, 0);
    }

    // ---- scale + causal mask --------------------------------------------
    const int qwbase = q0 + wid * 32;
    const bool need_mask = (key0 + 63) > qwbase;
#pragma unroll
    for (int mi = 0; mi < 2; ++mi)
#pragma unroll
      for (int nj = 0; nj < 4; ++nj) {
        int kcol = key0 + nj * 16 + l16;
#pragma unroll
        for (int r = 0; r < 4; ++r) {
          float v = sf[mi][nj][r] * ATTN_SCALE;
          if (need_mask) {
            int qrow = qwbase + mi * 16 + lg * 4 + r;
            if (kcol > qrow) v = -INFINITY;
          }
          sf[mi][nj][r] = v;
        }
      }

    // ---- online softmax --------------------------------------------------
#pragma unroll
    for (int mi = 0; mi < 2; ++mi) {
      float alpha[4];
#pragma unroll
      for (int r = 0; r < 4; ++r) {
        float m0 = fmaxf(fmaxf(sf[mi][0][r], sf[mi][1][r]),
                         fmaxf(sf[mi][2][r], sf[mi][3][r]));
#pragma unroll
        for (int off = 1; off < 16; off <<= 1)
          m0 = fmaxf(m0, __shfl_xor(m0, off, 64));
        float mn = fmaxf(mrun[mi][r], m0);
        alpha[r] = __expf(mrun[mi][r] - mn);   // exp(-inf)=0 on first tile
        mrun[mi][r] = mn;
      }
      float rs[4] = {0.f, 0.f, 0.f, 0.f};
#pragma unroll
      for (int nj = 0; nj < 4; ++nj) {
        int colb = nj * 16 + l16;
        int ch = colb >> 3, cb = colb & 7;
#pragma unroll
        for (int r = 0; r < 4; ++r) {
          float p = __expf(sf[mi][nj][r] - mrun[mi][r]);
          rs[r] += p;
          int prow = mi * 16 + lg * 4 + r;
          sm.Ps[wid * 2048 + prow * 64 + ((ch ^ (prow & 7)) << 3) + cb] = f2bf(p);
        }
      }
#pragma unroll
      for (int r = 0; r < 4; ++r) {
        float s0 = rs[r];
#pragma unroll
        for (int off = 1; off < 16; off <<= 1)
          s0 += __shfl_xor(s0, off, 64);
        lrun[mi][r] = lrun[mi][r] * alpha[r] + s0;
      }
#pragma unroll
      for (int dj = 0; dj < 8; ++dj)
#pragma unroll
        for (int r = 0; r < 4; ++r) accO[mi][dj][r] *= alpha[r];
    }

    // ---- PV --------------------------------------------------------------
#pragma unroll
    for (int ks = 0; ks < 2; ++ks) {
      bf16x8 ap[2], bv[8];
#pragma unroll
      for (int mi = 0; mi < 2; ++mi) {
        int r = mi * 16 + l16;
        ap[mi] = *reinterpret_cast<const bf16x8*>(
            &sm.Ps[wid * 2048 + r * 64 + (((ks * 4 + lg) ^ (r & 7)) << 3)]);
      }
#pragma unroll
      for (int dj = 0; dj < 8; ++dj) {
        int r = dj * 16 + l16;
        bv[dj] = *reinterpret_cast<const bf16x8*>(
            &sm.Vts[r * 64 + (((ks * 4 + lg) ^ (r & 7)) << 3)]);
      }
#pragma unroll
      for (int mi = 0; mi < 2; ++mi)
#pragma unroll
        for (int dj = 0; dj < 8; ++dj)
          accO[mi][dj] = __builtin_amdgcn_mfma_f32_16x16x32_bf16(ap[mi], bv[dj], accO[mi][dj], 0, 0, 0);
    }
  }

  // ---- epilogue: AO[b*S+q][h*DK+d] = accO / l ---------------------------
#pragma unroll
  for (int mi = 0; mi < 2; ++mi) {
    float inv[4];
#pragma unroll
    for (int r = 0; r < 4; ++r) inv[r] = 1.0f / lrun[mi][r];
#pragma unroll
    for (int dj = 0; dj < 8; ++dj) {
      int colg = h * DK + dj * 16 + l16;
#pragma unroll
      for (int r = 0; r < 4; ++r) {
        int qpos = q0 + wid * 32 + mi * 16 + lg * 4 + r;
        AO[((size_t)(b * SEQ + qpos)) * DIM + colg] = f2bf(accO[mi][dj][r] * inv[r]);
      }
    }
  }
}

// ---------------------------------------------------------------------------
extern "C" void kernel_launch(void* const* d_in, const int* in_sizes, int n_in,
                              void* d_out, int out_size, void* d_ws, size_t ws_size,
                              hipStream_t stream) {
  const float* x  = (const float*)d_in[0];
  const float* wq = (const float*)d_in[1];
  const float* wk = (const float*)d_in[2];
  const float* wv = (const float*)d_in[3];
  const float* wo = (const float*)d_in[4];

  // Outputs are FLOAT32: out [B,S,DIM], K [B,H,S,DK], V [B,H,S,DK].
  float* outF = (float*)d_out;
  float* outK = outF + TSZ;
  float* outV = outF + 2 * TSZ;

  // bf16 Q/K copies live in the (dead until final GEMM) out[0] slot:
  // byte range [0, 4*TSZ) holds two bf16 tensors of TSZ elements each.
  unsigned short* qb = (unsigned short*)outF;
  unsigned short* kb = qb + TSZ;

  // ws (bf16 elems), total 2*TSZ + WSZ = 41.9 MB (proven footprint):
  unsigned short* xb  = (unsigned short*)d_ws;  // converted x; later VT
  unsigned short* aop = xb + TSZ;               // AO (attn output staging)
  unsigned short* wb  = xb + 2 * TSZ;           // jit-converted weight
  unsigned short* vtb = xb;                     // VT over xb (x dead post-QKV)

  dim3 blk(256);
  dim3 ggrid(16, 32);
  const int cvtW = (int)(WSZ / 2048), n8W = (int)(WSZ / 8);

  cvt_f32_bf16<<<dim3((int)(TSZ / 2048)), blk, 0, stream>>>(x, xb, (int)(TSZ / 8));

  cvt_f32_bf16<<<dim3(cvtW), blk, 0, stream>>>(wq, wb, n8W);
  gemm_rope<1><<<ggrid, blk, 0, stream>>>(xb, wb, qb, nullptr);       // Q bf16

  cvt_f32_bf16<<<dim3(cvtW), blk, 0, stream>>>(wk, wb, n8W);
  gemm_rope<2><<<ggrid, blk, 0, stream>>>(xb, wb, kb, outK);          // K f32+bf16

  cvt_f32_bf16<<<dim3(cvtW), blk, 0, stream>>>(wv, wb, n8W);
  gemm_rope<3><<<ggrid, blk, 0, stream>>>(xb, wb, nullptr, outV);     // V f32

  vtrans<<<dim3(32, 32), blk, 0, stream>>>(outV, vtb);                // VT bf16

  attn_fused<<<dim3(16, 32), blk, 0, stream>>>(qb, kb, vtb, aop);

  cvt_f32_bf16<<<dim3(cvtW), blk, 0, stream>>>(wo, wb, n8W);
  gemm_rope<0><<<ggrid, blk, 0, stream>>>(aop, wb, nullptr, outF);    // final f32
}

// Round 8
// 643.757 us; speedup vs baseline: 9.2724x; 1.4165x over previous
//
#include <hip/hip_runtime.h>
#include <stdint.h>

typedef __bf16 bf16x8 __attribute__((ext_vector_type(8)));
typedef float f32x4 __attribute__((ext_vector_type(4)));

#define DEV __device__ __forceinline__
#define CAST_G(p) (const __attribute__((address_space(1))) unsigned int*)(p)
#define CAST_L(p) (__attribute__((address_space(3))) unsigned int*)(p)

constexpr int SEQ = 2048;
constexpr int DIM = 2048;
constexpr int NH  = 16;
constexpr int DK  = 128;
constexpr int BATCH = 2;
constexpr size_t TSZ = (size_t)BATCH * SEQ * DIM;   // 8388608 elements
constexpr size_t WSZ = (size_t)DIM * DIM;           // 4194304 elements per weight
constexpr float ATTN_SCALE = 0.08838834764831845f;  // 1/sqrt(128)

DEV unsigned short f2bf(float f) {
  unsigned int u = __float_as_uint(f);
  unsigned int r = (u + 0x7fffu + ((u >> 16) & 1u)) >> 16;
  return (unsigned short)r;
}

// ---------------------------------------------------------------------------
// fp32 -> bf16 (RTNE), 8 elements/thread, vectorized.
// ---------------------------------------------------------------------------
__global__ __launch_bounds__(256)
void cvt_f32_bf16(const float* __restrict__ src, unsigned short* __restrict__ dst,
                  int n8) {
  int i = blockIdx.x * 256 + threadIdx.x;
  if (i >= n8) return;
  float4 a = *reinterpret_cast<const float4*>(src + (size_t)i * 8);
  float4 b = *reinterpret_cast<const float4*>(src + (size_t)i * 8 + 4);
  unsigned short o[8];
  o[0] = f2bf(a.x); o[1] = f2bf(a.y); o[2] = f2bf(a.z); o[3] = f2bf(a.w);
  o[4] = f2bf(b.x); o[5] = f2bf(b.y); o[6] = f2bf(b.z); o[7] = f2bf(b.w);
  *reinterpret_cast<uint4*>(dst + (size_t)i * 8) = *reinterpret_cast<const uint4*>(o);
}

// ---------------------------------------------------------------------------
// GEMM: C[M,Nc] = A[M,K] * W[Nc,K]^T   (row-major, bf16 in, fp32 acc)
// 128x128 tile, BK=64, 4 waves (2x2).  Staging via global_load_lds(16B) with
// PRE-SWIZZLED SOURCE (involution c8^=(r&7)); LDS dest linear; reads XOR'd.
// MODE 0: plain row-major f32 store to Df            (WO projection)
// MODE 1: RoPE -> scatter [B,H,S,DK] bf16 to Db      (Q)
// MODE 2: RoPE -> scatter f32 to Df AND bf16 to Db   (K)
// MODE 3: scatter f32 to Df                          (V)
// ---------------------------------------------------------------------------
template <int MODE>
__global__ __launch_bounds__(256, 2)
void gemm_rope(const unsigned short* __restrict__ A,
               const unsigned short* __restrict__ W,
               unsigned short* __restrict__ Db,
               float* __restrict__ Df) {
  __shared__ __align__(16) unsigned short As[128 * 64];
  __shared__ __align__(16) unsigned short Bs[128 * 64];

  const int t = threadIdx.x;
  const int lane = t & 63;
  const int wid = t >> 6;
  const int wr = (wid >> 1) << 6;   // 0 / 64
  const int wc = (wid & 1) << 6;
  const int l16 = lane & 15, lg = lane >> 4;
  const int row0 = blockIdx.y * 128;
  const int col0 = blockIdx.x * 128;

  // staging geometry: per call i (0..3), linear 16B-chunk L = i*256 + t,
  // row r = 32*i + (t>>3), LDS chunk slot c8s = t&7, source chunk
  // c8 = c8s ^ (r&7) = (t&7) ^ ((t>>3)&7)  (32*i preserves r&7).
  const int srow = t >> 3;                         // 0..31
  const int scol = ((t & 7) ^ (srow & 7)) << 3;    // pre-swizzled src elem off
  const unsigned short* Asrc = A + (size_t)(row0 + srow) * DIM + scol;
  const unsigned short* Wsrc = W + (size_t)(col0 + srow) * DIM + scol;

  f32x4 acc[4][4] = {};

  for (int k0 = 0; k0 < DIM; k0 += 64) {
    __syncthreads();
#pragma unroll
    for (int i = 0; i < 4; ++i) {
      __builtin_amdgcn_global_load_lds(CAST_G(Asrc + (size_t)i * 32 * DIM + k0),
                                       CAST_L(As + i * 2048 + wid * 512), 16, 0, 0);
      __builtin_amdgcn_global_load_lds(CAST_G(Wsrc + (size_t)i * 32 * DIM + k0),
                                       CAST_L(Bs + i * 2048 + wid * 512), 16, 0, 0);
    }
    __syncthreads();
#pragma unroll
    for (int ks = 0; ks < 2; ++ks) {
      bf16x8 af[4], bfr[4];
#pragma unroll
      for (int i = 0; i < 4; ++i) {
        int ra = wr + i * 16 + l16;
        af[i] = *reinterpret_cast<const bf16x8*>(&As[ra * 64 + (((ks * 4 + lg) ^ (ra & 7)) << 3)]);
        int rb = wc + i * 16 + l16;
        bfr[i] = *reinterpret_cast<const bf16x8*>(&Bs[rb * 64 + (((ks * 4 + lg) ^ (rb & 7)) << 3)]);
      }
#pragma unroll
      for (int i = 0; i < 4; ++i)
#pragma unroll
        for (int j = 0; j < 4; ++j)
          acc[i][j] = __builtin_amdgcn_mfma_f32_16x16x32_bf16(af[i], bfr[j], acc[i][j], 0, 0, 0);
    }
  }

  if (MODE == 0) {
#pragma unroll
    for (int i = 0; i < 4; ++i)
#pragma unroll
      for (int j = 0; j < 4; ++j) {
        int colg = col0 + wc + j * 16 + l16;
#pragma unroll
        for (int r = 0; r < 4; ++r) {
          int rowg = row0 + wr + i * 16 + lg * 4 + r;
          Df[(size_t)rowg * DIM + colg] = acc[i][j][r];
        }
      }
  } else {
#pragma unroll
    for (int j = 0; j < 4; ++j) {
      int colg = col0 + wc + j * 16 + l16;
      int jj = (colg >> 1) & 63;
      float invf = __expf((float)jj * -0.14391156831212787f);  // 10000^(-jj/64)
#pragma unroll
      for (int i = 0; i < 4; ++i) {
#pragma unroll
        for (int r = 0; r < 4; ++r) {
          int rowg = row0 + wr + i * 16 + lg * 4 + r;
          float v = acc[i][j][r];
          float outv;
          if (MODE == 1 || MODE == 2) {
            float p = __shfl_xor(v, 1, 64);
            int pos = rowg & (SEQ - 1);
            float ang = (float)pos * invf;
            float sn, cs;
            __sincosf(ang, &sn, &cs);
            outv = (colg & 1) ? fmaf(p, sn, v * cs) : fmaf(v, cs, -(p * sn));
          } else {
            outv = v;
          }
          int b = rowg >> 11, pos = rowg & (SEQ - 1);
          int h = colg >> 7, d = colg & (DK - 1);
          size_t idx = (((size_t)(b * NH + h)) * SEQ + pos) * DK + d;
          if (MODE == 1) Db[idx] = f2bf(outv);
          if (MODE == 2) { Df[idx] = outv; Db[idx] = f2bf(outv); }
          if (MODE == 3) Df[idx] = outv;
        }
      }
    }
  }
}

// ---------------------------------------------------------------------------
// V^T builder: V [B,H,S,DK] f32 -> VT [B,H,DK,S] bf16
// ---------------------------------------------------------------------------
__global__ __launch_bounds__(256, 2)
void vtrans(const float* __restrict__ V, unsigned short* __restrict__ VT) {
  __shared__ float vs[64 * 128];  // 32KB [pos][d]
  const int t = threadIdx.x;
  const int bh = blockIdx.y;
  const int p0 = blockIdx.x * 64;
  const float* src = V + ((size_t)bh * SEQ + p0) * DK;
#pragma unroll
  for (int s = 0; s < 8; ++s) {
    int id = s * 256 + t;
    *reinterpret_cast<float4*>(&vs[id * 4]) = *reinterpret_cast<const float4*>(&src[id * 4]);
  }
  __syncthreads();
  const int w = t >> 6, l = t & 63;
  unsigned short* dstb = VT + (size_t)bh * DK * SEQ + p0;
#pragma unroll
  for (int it = 0; it < 4; ++it) {
    int d = w * 32 + (it & 1) * 16 + (l & 15);
    int kc = (it >> 1) * 4 + (l >> 4);
    unsigned short tmp[8];
#pragma unroll
    for (int j = 0; j < 8; ++j) tmp[j] = f2bf(vs[(kc * 8 + j) * DK + d]);
    *reinterpret_cast<uint4*>(&dstb[(size_t)d * SEQ + kc * 8]) =
        *reinterpret_cast<const uint4*>(tmp);
  }
}

// ---------------------------------------------------------------------------
// Fused causal flash attention.  Q [B,H,S,DK] bf16 (roped, -> registers),
// K bf16, VT [B,H,DK,S] bf16 -> AO [B*S, DIM] bf16.
// Block: 256 thr / 4 waves; Q-tile 128 (32 rows/wave); KV-tile 64.
// LDS 48KB -> 3 blocks/CU.
// ---------------------------------------------------------------------------
struct __align__(16) AttnSmem {
  unsigned short Ks[64 * 128];    // 16KB  [key][dk], swizzled
  unsigned short Vts[128 * 64];   // 16KB  [d][key], swizzled
  unsigned short Ps[4 * 32 * 64]; // 16KB  per-wave P [q][key], swizzled
};

__global__ __launch_bounds__(256, 3)
void attn_fused(const unsigned short* __restrict__ Q,
                const unsigned short* __restrict__ K,
                const unsigned short* __restrict__ VT,
                unsigned short* __restrict__ AO) {
  __shared__ AttnSmem sm;
  const int t = threadIdx.x;
  const int lane = t & 63;
  const int wid = t >> 6;
  const int l16 = lane & 15, lg = lane >> 4;
  const int qt = (int)(gridDim.x - 1 - blockIdx.x);  // heavy tiles first
  const int bh = blockIdx.y;
  const int b = bh >> 4, h = bh & 15;
  const int q0 = qt * 128;

  const unsigned short* Qbase = Q + ((size_t)bh * SEQ + q0) * DK;
  const unsigned short* Kbase = K + (size_t)bh * SEQ * DK;
  const unsigned short* VTbase = VT + (size_t)bh * DK * SEQ;

  // Q fragments straight to registers (read once): qf[mi][ks]
  bf16x8 qf[2][4];
#pragma unroll
  for (int mi = 0; mi < 2; ++mi)
#pragma unroll
    for (int ks = 0; ks < 4; ++ks)
      qf[mi][ks] = *reinterpret_cast<const bf16x8*>(
          Qbase + (size_t)(wid * 32 + mi * 16 + l16) * DK + (ks * 4 + lg) * 8);

  f32x4 accO[2][8] = {};
  float mrun[2][4], lrun[2][4];
#pragma unroll
  for (int mi = 0; mi < 2; ++mi)
#pragma unroll
    for (int r = 0; r < 4; ++r) { mrun[mi][r] = -INFINITY; lrun[mi][r] = 0.f; }

  const int nkv = (q0 + 128) / 64;

  uint4 pk[4], pv[4];
#pragma unroll
  for (int s = 0; s < 4; ++s) {
    int id = s * 256 + t;
    int rk = id >> 4, ck = id & 15;
    pk[s] = *reinterpret_cast<const uint4*>(Kbase + (size_t)rk * DK + (ck << 3));
    int rv = id >> 3, cv = id & 7;
    pv[s] = *reinterpret_cast<const uint4*>(VTbase + (size_t)rv * SEQ + (cv << 3));
  }

  for (int kt = 0; kt < nkv; ++kt) {
    const int key0 = kt * 64;
    __syncthreads();
#pragma unroll
    for (int s = 0; s < 4; ++s) {
      int id = s * 256 + t;
      int rk = id >> 4, ck = id & 15;
      *reinterpret_cast<uint4*>(&sm.Ks[rk * 128 + ((ck ^ (rk & 7)) << 3)]) = pk[s];
      int rv = id >> 3, cv = id & 7;
      *reinterpret_cast<uint4*>(&sm.Vts[rv * 64 + ((cv ^ (rv & 7)) << 3)]) = pv[s];
    }
    __syncthreads();
    if (kt + 1 < nkv) {
      const int kn = key0 + 64;
#pragma unroll
      for (int s = 0; s < 4; ++s) {
        int id = s * 256 + t;
        int rk = id >> 4, ck = id & 15;
        pk[s] = *reinterpret_cast<const uint4*>(Kbase + (size_t)(kn + rk) * DK + (ck << 3));
        int rv = id >> 3, cv = id & 7;
        pv[s] = *reinterpret_cast<const uint4*>(VTbase + (size_t)rv * SEQ + kn + (cv << 3));
      }
    }

    // ---- S = Q K^T -------------------------------------------------------
    f32x4 sf[2][4] = {};
#pragma unroll
    for (int ks = 0; ks < 4; ++ks) {
      bf16x8 bk[4];
#pragma unroll
      for (int nj = 0; nj < 4; ++nj) {
        int r = nj * 16 + l16;
        bk[nj] = *reinterpret_cast<const bf16x8*>(
            &sm.Ks[r * 128 + (((ks * 4 + lg) ^ (r & 7)) << 3)]);
      }
#pragma unroll
      for (int mi = 0; mi < 2; ++mi)
#pragma unroll
        for (int nj = 0; nj < 4; ++nj)
          sf[mi][nj] = __builtin_amdgcn_mfma_f32_16x16x32_bf16(qf[mi][ks], bk[nj], sf[mi][nj], 0, 0, 0);
    }

    // ---- scale + causal mask --------------------------------------------
    const int qwbase = q0 + wid * 32;
    const bool need_mask = (key0 + 63) > qwbase;
#pragma unroll
    for (int mi = 0; mi < 2; ++mi)
#pragma unroll
      for (int nj = 0; nj < 4; ++nj) {
        int kcol = key0 + nj * 16 + l16;
#pragma unroll
        for (int r = 0; r < 4; ++r) {
          float v = sf[mi][nj][r] * ATTN_SCALE;
          if (need_mask) {
            int qrow = qwbase + mi * 16 + lg * 4 + r;
            if (kcol > qrow) v = -INFINITY;
          }
          sf[mi][nj][r] = v;
        }
      }

    // ---- online softmax --------------------------------------------------
#pragma unroll
    for (int mi = 0; mi < 2; ++mi) {
      float alpha[4];
#pragma unroll
      for (int r = 0; r < 4; ++r) {
        float m0 = fmaxf(fmaxf(sf[mi][0][r], sf[mi][1][r]),
                         fmaxf(sf[mi][2][r], sf[mi][3][r]));
#pragma unroll
        for (int off = 1; off < 16; off <<= 1)
          m0 = fmaxf(m0, __shfl_xor(m0, off, 64));
        float mn = fmaxf(mrun[mi][r], m0);
        alpha[r] = __expf(mrun[mi][r] - mn);   // exp(-inf)=0 on first tile
        mrun[mi][r] = mn;
      }
      float rs[4] = {0.f, 0.f, 0.f, 0.f};
#pragma unroll
      for (int nj = 0; nj < 4; ++nj) {
        int colb = nj * 16 + l16;
        int ch = colb >> 3, cb = colb & 7;
#pragma unroll
        for (int r = 0; r < 4; ++r) {
          float p = __expf(sf[mi][nj][r] - mrun[mi][r]);
          rs[r] += p;
          int prow = mi * 16 + lg * 4 + r;
          sm.Ps[wid * 2048 + prow * 64 + ((ch ^ (prow & 7)) << 3) + cb] = f2bf(p);
        }
      }
#pragma unroll
      for (int r = 0; r < 4; ++r) {
        float s0 = rs[r];
#pragma unroll
        for (int off = 1; off < 16; off <<= 1)
          s0 += __shfl_xor(s0, off, 64);
        lrun[mi][r] = lrun[mi][r] * alpha[r] + s0;
      }
#pragma unroll
      for (int dj = 0; dj < 8; ++dj)
#pragma unroll
        for (int r = 0; r < 4; ++r) accO[mi][dj][r] *= alpha[r];
    }

    // ---- PV --------------------------------------------------------------
#pragma unroll
    for (int ks = 0; ks < 2; ++ks) {
      bf16x8 ap[2], bv[8];
#pragma unroll
      for (int mi = 0; mi < 2; ++mi) {
        int r = mi * 16 + l16;
        ap[mi] = *reinterpret_cast<const bf16x8*>(
            &sm.Ps[wid * 2048 + r * 64 + (((ks * 4 + lg) ^ (r & 7)) << 3)]);
      }
#pragma unroll
      for (int dj = 0; dj < 8; ++dj) {
        int r = dj * 16 + l16;
        bv[dj] = *reinterpret_cast<const bf16x8*>(
            &sm.Vts[r * 64 + (((ks * 4 + lg) ^ (r & 7)) << 3)]);
      }
#pragma unroll
      for (int mi = 0; mi < 2; ++mi)
#pragma unroll
        for (int dj = 0; dj < 8; ++dj)
          accO[mi][dj] = __builtin_amdgcn_mfma_f32_16x16x32_bf16(ap[mi], bv[dj], accO[mi][dj], 0, 0, 0);
    }
  }

  // ---- epilogue ---------------------------------------------------------
#pragma unroll
  for (int mi = 0; mi < 2; ++mi) {
    float inv[4];
#pragma unroll
    for (int r = 0; r < 4; ++r) inv[r] = 1.0f / lrun[mi][r];
#pragma unroll
    for (int dj = 0; dj < 8; ++dj) {
      int colg = h * DK + dj * 16 + l16;
#pragma unroll
      for (int r = 0; r < 4; ++r) {
        int qpos = q0 + wid * 32 + mi * 16 + lg * 4 + r;
        AO[((size_t)(b * SEQ + qpos)) * DIM + colg] = f2bf(accO[mi][dj][r] * inv[r]);
      }
    }
  }
}

// ---------------------------------------------------------------------------
extern "C" void kernel_launch(void* const* d_in, const int* in_sizes, int n_in,
                              void* d_out, int out_size, void* d_ws, size_t ws_size,
                              hipStream_t stream) {
  const float* x  = (const float*)d_in[0];
  const float* wq = (const float*)d_in[1];
  const float* wk = (const float*)d_in[2];
  const float* wv = (const float*)d_in[3];
  const float* wo = (const float*)d_in[4];

  // Outputs are FLOAT32: out [B,S,DIM], K [B,H,S,DK], V [B,H,S,DK].
  float* outF = (float*)d_out;
  float* outK = outF + TSZ;
  float* outV = outF + 2 * TSZ;

  // bf16 Q/K copies live in the (dead until final GEMM) out[0] f32 slot.
  unsigned short* qb = (unsigned short*)outF;
  unsigned short* kb = qb + TSZ;

  // ws (bf16 elems), total 2*TSZ + WSZ = 41.9 MB (proven footprint):
  unsigned short* xb  = (unsigned short*)d_ws;  // converted x; later VT
  unsigned short* aop = xb + TSZ;               // AO (attn output staging)
  unsigned short* wb  = xb + 2 * TSZ;           // jit-converted weight
  unsigned short* vtb = xb;                     // VT over xb (x dead post-QKV)

  dim3 blk(256);
  dim3 ggrid(16, 32);
  const int cvtW = (int)(WSZ / 2048), n8W = (int)(WSZ / 8);

  cvt_f32_bf16<<<dim3((int)(TSZ / 2048)), blk, 0, stream>>>(x, xb, (int)(TSZ / 8));

  cvt_f32_bf16<<<dim3(cvtW), blk, 0, stream>>>(wq, wb, n8W);
  gemm_rope<1><<<ggrid, blk, 0, stream>>>(xb, wb, qb, nullptr);       // Q bf16

  cvt_f32_bf16<<<dim3(cvtW), blk, 0, stream>>>(wk, wb, n8W);
  gemm_rope<2><<<ggrid, blk, 0, stream>>>(xb, wb, kb, outK);          // K f32+bf16

  cvt_f32_bf16<<<dim3(cvtW), blk, 0, stream>>>(wv, wb, n8W);
  gemm_rope<3><<<ggrid, blk, 0, stream>>>(xb, wb, nullptr, outV);     // V f32

  vtrans<<<dim3(32, 32), blk, 0, stream>>>(outV, vtb);                // VT bf16

  attn_fused<<<dim3(16, 32), blk, 0, stream>>>(qb, kb, vtb, aop);

  cvt_f32_bf16<<<dim3(cvtW), blk, 0, stream>>>(wo, wb, n8W);
  gemm_rope<0><<<ggrid, blk, 0, stream>>>(aop, wb, nullptr, outF);    // final f32
}

// Round 9
// 628.178 us; speedup vs baseline: 9.5024x; 1.0248x over previous
//
#include <hip/hip_runtime.h>
#include <stdint.h>

typedef __bf16 bf16x8 __attribute__((ext_vector_type(8)));
typedef float f32x4 __attribute__((ext_vector_type(4)));

#define DEV __device__ __forceinline__
#define CAST_G(p) (const __attribute__((address_space(1))) unsigned int*)(p)
#define CAST_L(p) (__attribute__((address_space(3))) unsigned int*)(p)

constexpr int SEQ = 2048;
constexpr int DIM = 2048;
constexpr int NH  = 16;
constexpr int DK  = 128;
constexpr int BATCH = 2;
constexpr size_t TSZ = (size_t)BATCH * SEQ * DIM;   // 8388608 elements
constexpr size_t WSZ = (size_t)DIM * DIM;           // 4194304 elements per weight
constexpr float ATTN_SCALE = 0.08838834764831845f;  // 1/sqrt(128)

DEV unsigned short f2bf(float f) {
  unsigned int u = __float_as_uint(f);
  unsigned int r = (u + 0x7fffu + ((u >> 16) & 1u)) >> 16;
  return (unsigned short)r;
}

// ---------------------------------------------------------------------------
// fp32 -> bf16 (RTNE), 8 elements/thread, vectorized.
// ---------------------------------------------------------------------------
__global__ __launch_bounds__(256)
void cvt_f32_bf16(const float* __restrict__ src, unsigned short* __restrict__ dst,
                  int n8) {
  int i = blockIdx.x * 256 + threadIdx.x;
  if (i >= n8) return;
  float4 a = *reinterpret_cast<const float4*>(src + (size_t)i * 8);
  float4 b = *reinterpret_cast<const float4*>(src + (size_t)i * 8 + 4);
  unsigned short o[8];
  o[0] = f2bf(a.x); o[1] = f2bf(a.y); o[2] = f2bf(a.z); o[3] = f2bf(a.w);
  o[4] = f2bf(b.x); o[5] = f2bf(b.y); o[6] = f2bf(b.z); o[7] = f2bf(b.w);
  *reinterpret_cast<uint4*>(dst + (size_t)i * 8) = *reinterpret_cast<const uint4*>(o);
}

// ---------------------------------------------------------------------------
// GEMM: C[M,Nc] = A[M,K] * W[Nc,K]^T   (row-major, bf16 in, fp32 acc)
// 128x128 tile, BK=64, 4 waves (2x2).  Staging via global_load_lds(16B) with
// PRE-SWIZZLED SOURCE (involution c8^=(r&7)); LDS dest linear; reads XOR'd.
// MODE 0: plain row-major f32 store to Df            (WO projection)
// MODE 1: RoPE -> scatter [B,H,S,DK] bf16 to Db      (Q)
// MODE 2: RoPE -> scatter f32 to Df AND bf16 to Db   (K)
// MODE 3: scatter f32 to Df                          (V)
// ---------------------------------------------------------------------------
template <int MODE>
__global__ __launch_bounds__(256, 2)
void gemm_rope(const unsigned short* __restrict__ A,
               const unsigned short* __restrict__ W,
               unsigned short* __restrict__ Db,
               float* __restrict__ Df) {
  __shared__ __align__(16) unsigned short As[128 * 64];
  __shared__ __align__(16) unsigned short Bs[128 * 64];

  const int t = threadIdx.x;
  const int lane = t & 63;
  const int wid = t >> 6;
  const int wr = (wid >> 1) << 6;   // 0 / 64
  const int wc = (wid & 1) << 6;
  const int l16 = lane & 15, lg = lane >> 4;
  const int row0 = blockIdx.y * 128;
  const int col0 = blockIdx.x * 128;

  const int srow = t >> 3;                         // 0..31
  const int scol = ((t & 7) ^ (srow & 7)) << 3;    // pre-swizzled src elem off
  const unsigned short* Asrc = A + (size_t)(row0 + srow) * DIM + scol;
  const unsigned short* Wsrc = W + (size_t)(col0 + srow) * DIM + scol;

  f32x4 acc[4][4] = {};

  for (int k0 = 0; k0 < DIM; k0 += 64) {
    __syncthreads();
#pragma unroll
    for (int i = 0; i < 4; ++i) {
      __builtin_amdgcn_global_load_lds(CAST_G(Asrc + (size_t)i * 32 * DIM + k0),
                                       CAST_L(As + i * 2048 + wid * 512), 16, 0, 0);
      __builtin_amdgcn_global_load_lds(CAST_G(Wsrc + (size_t)i * 32 * DIM + k0),
                                       CAST_L(Bs + i * 2048 + wid * 512), 16, 0, 0);
    }
    __syncthreads();
#pragma unroll
    for (int ks = 0; ks < 2; ++ks) {
      bf16x8 af[4], bfr[4];
#pragma unroll
      for (int i = 0; i < 4; ++i) {
        int ra = wr + i * 16 + l16;
        af[i] = *reinterpret_cast<const bf16x8*>(&As[ra * 64 + (((ks * 4 + lg) ^ (ra & 7)) << 3)]);
        int rb = wc + i * 16 + l16;
        bfr[i] = *reinterpret_cast<const bf16x8*>(&Bs[rb * 64 + (((ks * 4 + lg) ^ (rb & 7)) << 3)]);
      }
#pragma unroll
      for (int i = 0; i < 4; ++i)
#pragma unroll
        for (int j = 0; j < 4; ++j)
          acc[i][j] = __builtin_amdgcn_mfma_f32_16x16x32_bf16(af[i], bfr[j], acc[i][j], 0, 0, 0);
    }
  }

  if (MODE == 0) {
#pragma unroll
    for (int i = 0; i < 4; ++i)
#pragma unroll
      for (int j = 0; j < 4; ++j) {
        int colg = col0 + wc + j * 16 + l16;
#pragma unroll
        for (int r = 0; r < 4; ++r) {
          int rowg = row0 + wr + i * 16 + lg * 4 + r;
          Df[(size_t)rowg * DIM + colg] = acc[i][j][r];
        }
      }
  } else {
#pragma unroll
    for (int j = 0; j < 4; ++j) {
      int colg = col0 + wc + j * 16 + l16;
      int jj = (colg >> 1) & 63;
      float invf = __expf((float)jj * -0.14391156831212787f);  // 10000^(-jj/64)
#pragma unroll
      for (int i = 0; i < 4; ++i) {
#pragma unroll
        for (int r = 0; r < 4; ++r) {
          int rowg = row0 + wr + i * 16 + lg * 4 + r;
          float v = acc[i][j][r];
          float outv;
          if (MODE == 1 || MODE == 2) {
            float p = __shfl_xor(v, 1, 64);
            int pos = rowg & (SEQ - 1);
            float ang = (float)pos * invf;
            float sn, cs;
            __sincosf(ang, &sn, &cs);
            outv = (colg & 1) ? fmaf(p, sn, v * cs) : fmaf(v, cs, -(p * sn));
          } else {
            outv = v;
          }
          int b = rowg >> 11, pos = rowg & (SEQ - 1);
          int h = colg >> 7, d = colg & (DK - 1);
          size_t idx = (((size_t)(b * NH + h)) * SEQ + pos) * DK + d;
          if (MODE == 1) Db[idx] = f2bf(outv);
          if (MODE == 2) { Df[idx] = outv; Db[idx] = f2bf(outv); }
          if (MODE == 3) Df[idx] = outv;
        }
      }
    }
  }
}

// ---------------------------------------------------------------------------
// V^T builder: V [B,H,S,DK] f32 -> VT [B,H,DK,S] bf16
// ---------------------------------------------------------------------------
__global__ __launch_bounds__(256, 2)
void vtrans(const float* __restrict__ V, unsigned short* __restrict__ VT) {
  __shared__ float vs[64 * 128];  // 32KB [pos][d]
  const int t = threadIdx.x;
  const int bh = blockIdx.y;
  const int p0 = blockIdx.x * 64;
  const float* src = V + ((size_t)bh * SEQ + p0) * DK;
#pragma unroll
  for (int s = 0; s < 8; ++s) {
    int id = s * 256 + t;
    *reinterpret_cast<float4*>(&vs[id * 4]) = *reinterpret_cast<const float4*>(&src[id * 4]);
  }
  __syncthreads();
  const int w = t >> 6, l = t & 63;
  unsigned short* dstb = VT + (size_t)bh * DK * SEQ + p0;
#pragma unroll
  for (int it = 0; it < 4; ++it) {
    int d = w * 32 + (it & 1) * 16 + (l & 15);
    int kc = (it >> 1) * 4 + (l >> 4);
    unsigned short tmp[8];
#pragma unroll
    for (int j = 0; j < 8; ++j) tmp[j] = f2bf(vs[(kc * 8 + j) * DK + d]);
    *reinterpret_cast<uint4*>(&dstb[(size_t)d * SEQ + kc * 8]) =
        *reinterpret_cast<const uint4*>(tmp);
  }
}

// ---------------------------------------------------------------------------
// Fused causal flash attention.  Q [B,H,S,DK] bf16 (roped, -> registers),
// K bf16, VT [B,H,DK,S] bf16 -> AO [B*S, DIM] bf16.
// Block: 256 thr / 4 waves; Q-tile 128 (32 rows/wave); KV-tile 64.
// XCD-chunked block swizzle: all 16 q-tiles of a bh on one XCD.
// LDS-staged vectorized epilogue (no partial-sector HBM writes).
// ---------------------------------------------------------------------------
struct __align__(16) AttnSmem {
  unsigned short Ks[64 * 128];    // 16KB  [key][dk], swizzled
  unsigned short Vts[128 * 64];   // 16KB  [d][key], swizzled
  unsigned short Ps[4 * 32 * 64]; // 16KB  per-wave P [q][key]; epilogue reuse
};

__global__ __launch_bounds__(256, 3)
void attn_fused(const unsigned short* __restrict__ Q,
                const unsigned short* __restrict__ K,
                const unsigned short* __restrict__ VT,
                unsigned short* __restrict__ AO) {
  __shared__ AttnSmem sm;
  const int t = threadIdx.x;
  const int lane = t & 63;
  const int wid = t >> 6;
  const int l16 = lane & 15, lg = lane >> 4;

  // XCD-chunked swizzle: lin%8 ~ XCD (heuristic). 64 blocks/XCD = 4 bh x 16 qt.
  const int lin = (int)(blockIdx.x + gridDim.x * blockIdx.y);  // 0..511
  const int xcd = lin & 7;
  const int idx = lin >> 3;                 // 0..63
  const int bh = xcd * 4 + (idx >> 4);      // 4 heads per XCD
  const int qt = 15 - (idx & 15);           // heavy tiles first
  const int b = bh >> 4, h = bh & 15;
  const int q0 = qt * 128;

  const unsigned short* Qbase = Q + ((size_t)bh * SEQ + q0) * DK;
  const unsigned short* Kbase = K + (size_t)bh * SEQ * DK;
  const unsigned short* VTbase = VT + (size_t)bh * DK * SEQ;

  // Q fragments straight to registers (read once): qf[mi][ks]
  bf16x8 qf[2][4];
#pragma unroll
  for (int mi = 0; mi < 2; ++mi)
#pragma unroll
    for (int ks = 0; ks < 4; ++ks)
      qf[mi][ks] = *reinterpret_cast<const bf16x8*>(
          Qbase + (size_t)(wid * 32 + mi * 16 + l16) * DK + (ks * 4 + lg) * 8);

  f32x4 accO[2][8] = {};
  float mrun[2][4], lrun[2][4];
#pragma unroll
  for (int mi = 0; mi < 2; ++mi)
#pragma unroll
    for (int r = 0; r < 4; ++r) { mrun[mi][r] = -INFINITY; lrun[mi][r] = 0.f; }

  const int nkv = (q0 + 128) / 64;

  uint4 pk[4], pv[4];
#pragma unroll
  for (int s = 0; s < 4; ++s) {
    int id = s * 256 + t;
    int rk = id >> 4, ck = id & 15;
    pk[s] = *reinterpret_cast<const uint4*>(Kbase + (size_t)rk * DK + (ck << 3));
    int rv = id >> 3, cv = id & 7;
    pv[s] = *reinterpret_cast<const uint4*>(VTbase + (size_t)rv * SEQ + (cv << 3));
  }

  for (int kt = 0; kt < nkv; ++kt) {
    const int key0 = kt * 64;
    __syncthreads();
#pragma unroll
    for (int s = 0; s < 4; ++s) {
      int id = s * 256 + t;
      int rk = id >> 4, ck = id & 15;
      *reinterpret_cast<uint4*>(&sm.Ks[rk * 128 + ((ck ^ (rk & 7)) << 3)]) = pk[s];
      int rv = id >> 3, cv = id & 7;
      *reinterpret_cast<uint4*>(&sm.Vts[rv * 64 + ((cv ^ (rv & 7)) << 3)]) = pv[s];
    }
    __syncthreads();
    if (kt + 1 < nkv) {
      const int kn = key0 + 64;
#pragma unroll
      for (int s = 0; s < 4; ++s) {
        int id = s * 256 + t;
        int rk = id >> 4, ck = id & 15;
        pk[s] = *reinterpret_cast<const uint4*>(Kbase + (size_t)(kn + rk) * DK + (ck << 3));
        int rv = id >> 3, cv = id & 7;
        pv[s] = *reinterpret_cast<const uint4*>(VTbase + (size_t)rv * SEQ + kn + (cv << 3));
      }
    }

    // ---- S = Q K^T -------------------------------------------------------
    f32x4 sf[2][4] = {};
#pragma unroll
    for (int ks = 0; ks < 4; ++ks) {
      bf16x8 bk[4];
#pragma unroll
      for (int nj = 0; nj < 4; ++nj) {
        int r = nj * 16 + l16;
        bk[nj] = *reinterpret_cast<const bf16x8*>(
            &sm.Ks[r * 128 + (((ks * 4 + lg) ^ (r & 7)) << 3)]);
      }
#pragma unroll
      for (int mi = 0; mi < 2; ++mi)
#pragma unroll
        for (int nj = 0; nj < 4; ++nj)
          sf[mi][nj] = __builtin_amdgcn_mfma_f32_16x16x32_bf16(qf[mi][ks], bk[nj], sf[mi][nj], 0, 0, 0);
    }

    // ---- scale + causal mask --------------------------------------------
    const int qwbase = q0 + wid * 32;
    const bool need_mask = (key0 + 63) > qwbase;
#pragma unroll
    for (int mi = 0; mi < 2; ++mi)
#pragma unroll
      for (int nj = 0; nj < 4; ++nj) {
        int kcol = key0 + nj * 16 + l16;
#pragma unroll
        for (int r = 0; r < 4; ++r) {
          float v = sf[mi][nj][r] * ATTN_SCALE;
          if (need_mask) {
            int qrow = qwbase + mi * 16 + lg * 4 + r;
            if (kcol > qrow) v = -INFINITY;
          }
          sf[mi][nj][r] = v;
        }
      }

    // ---- online softmax --------------------------------------------------
#pragma unroll
    for (int mi = 0; mi < 2; ++mi) {
      float alpha[4];
#pragma unroll
      for (int r = 0; r < 4; ++r) {
        float m0 = fmaxf(fmaxf(sf[mi][0][r], sf[mi][1][r]),
                         fmaxf(sf[mi][2][r], sf[mi][3][r]));
#pragma unroll
        for (int off = 1; off < 16; off <<= 1)
          m0 = fmaxf(m0, __shfl_xor(m0, off, 64));
        float mn = fmaxf(mrun[mi][r], m0);
        alpha[r] = __expf(mrun[mi][r] - mn);   // exp(-inf)=0 on first tile
        mrun[mi][r] = mn;
      }
      float rs[4] = {0.f, 0.f, 0.f, 0.f};
#pragma unroll
      for (int nj = 0; nj < 4; ++nj) {
        int colb = nj * 16 + l16;
        int ch = colb >> 3, cb = colb & 7;
#pragma unroll
        for (int r = 0; r < 4; ++r) {
          float p = __expf(sf[mi][nj][r] - mrun[mi][r]);
          rs[r] += p;
          int prow = mi * 16 + lg * 4 + r;
          sm.Ps[wid * 2048 + prow * 64 + ((ch ^ (prow & 7)) << 3) + cb] = f2bf(p);
        }
      }
#pragma unroll
      for (int r = 0; r < 4; ++r) {
        float s0 = rs[r];
#pragma unroll
        for (int off = 1; off < 16; off <<= 1)
          s0 += __shfl_xor(s0, off, 64);
        lrun[mi][r] = lrun[mi][r] * alpha[r] + s0;
      }
#pragma unroll
      for (int dj = 0; dj < 8; ++dj)
#pragma unroll
        for (int r = 0; r < 4; ++r) accO[mi][dj][r] *= alpha[r];
    }

    // ---- PV --------------------------------------------------------------
#pragma unroll
    for (int ks = 0; ks < 2; ++ks) {
      bf16x8 ap[2], bv[8];
#pragma unroll
      for (int mi = 0; mi < 2; ++mi) {
        int r = mi * 16 + l16;
        ap[mi] = *reinterpret_cast<const bf16x8*>(
            &sm.Ps[wid * 2048 + r * 64 + (((ks * 4 + lg) ^ (r & 7)) << 3)]);
      }
#pragma unroll
      for (int dj = 0; dj < 8; ++dj) {
        int r = dj * 16 + l16;
        bv[dj] = *reinterpret_cast<const bf16x8*>(
            &sm.Vts[r * 64 + (((ks * 4 + lg) ^ (r & 7)) << 3)]);
      }
#pragma unroll
      for (int mi = 0; mi < 2; ++mi)
#pragma unroll
        for (int dj = 0; dj < 8; ++dj)
          accO[mi][dj] = __builtin_amdgcn_mfma_f32_16x16x32_bf16(ap[mi], bv[dj], accO[mi][dj], 0, 0, 0);
    }
  }

  // ---- epilogue: per-wave LDS transpose -> contiguous uint4 stores -------
  unsigned short* Pw = &sm.Ps[wid * 2048];  // 16x128 tile per pass
#pragma unroll
  for (int mi = 0; mi < 2; ++mi) {
    float inv[4];
#pragma unroll
    for (int r = 0; r < 4; ++r) inv[r] = 1.0f / lrun[mi][r];
#pragma unroll
    for (int dj = 0; dj < 8; ++dj)
#pragma unroll
      for (int r = 0; r < 4; ++r)
        Pw[(lg * 4 + r) * 128 + dj * 16 + l16] = f2bf(accO[mi][dj][r] * inv[r]);
    // wave-internal write->read (same wave, compiler inserts lgkmcnt)
#pragma unroll
    for (int ps = 0; ps < 4; ++ps) {
      int row = ps * 4 + lg;               // 0..15
      uint4 v = *reinterpret_cast<const uint4*>(&Pw[row * 128 + l16 * 8]);
      int qpos = q0 + wid * 32 + mi * 16 + row;
      *reinterpret_cast<uint4*>(
          &AO[((size_t)(b * SEQ + qpos)) * DIM + h * DK + l16 * 8]) = v;
    }
  }
}

// ---------------------------------------------------------------------------
extern "C" void kernel_launch(void* const* d_in, const int* in_sizes, int n_in,
                              void* d_out, int out_size, void* d_ws, size_t ws_size,
                              hipStream_t stream) {
  const float* x  = (const float*)d_in[0];
  const float* wq = (const float*)d_in[1];
  const float* wk = (const float*)d_in[2];
  const float* wv = (const float*)d_in[3];
  const float* wo = (const float*)d_in[4];

  // Outputs are FLOAT32: out [B,S,DIM], K [B,H,S,DK], V [B,H,S,DK].
  float* outF = (float*)d_out;
  float* outK = outF + TSZ;
  float* outV = outF + 2 * TSZ;

  // bf16 Q/K copies live in the (dead until final GEMM) out[0] f32 slot.
  unsigned short* qb = (unsigned short*)outF;
  unsigned short* kb = qb + TSZ;

  // ws (bf16 elems), total 2*TSZ + WSZ = 41.9 MB (proven footprint):
  unsigned short* xb  = (unsigned short*)d_ws;  // converted x; later VT
  unsigned short* aop = xb + TSZ;               // AO (attn output staging)
  unsigned short* wb  = xb + 2 * TSZ;           // jit-converted weight
  unsigned short* vtb = xb;                     // VT over xb (x dead post-QKV)

  dim3 blk(256);
  dim3 ggrid(16, 32);
  const int cvtW = (int)(WSZ / 2048), n8W = (int)(WSZ / 8);

  cvt_f32_bf16<<<dim3((int)(TSZ / 2048)), blk, 0, stream>>>(x, xb, (int)(TSZ / 8));

  cvt_f32_bf16<<<dim3(cvtW), blk, 0, stream>>>(wq, wb, n8W);
  gemm_rope<1><<<ggrid, blk, 0, stream>>>(xb, wb, qb, nullptr);       // Q bf16

  cvt_f32_bf16<<<dim3(cvtW), blk, 0, stream>>>(wk, wb, n8W);
  gemm_rope<2><<<ggrid, blk, 0, stream>>>(xb, wb, kb, outK);          // K f32+bf16

  cvt_f32_bf16<<<dim3(cvtW), blk, 0, stream>>>(wv, wb, n8W);
  gemm_rope<3><<<ggrid, blk, 0, stream>>>(xb, wb, nullptr, outV);     // V f32

  vtrans<<<dim3(32, 32), blk, 0, stream>>>(outV, vtb);                // VT bf16

  attn_fused<<<dim3(16, 32), blk, 0, stream>>>(qb, kb, vtb, aop);

  cvt_f32_bf16<<<dim3(cvtW), blk, 0, stream>>>(wo, wb, n8W);
  gemm_rope<0><<<ggrid, blk, 0, stream>>>(aop, wb, nullptr, outF);    // final f32
}

// Round 10
// 397.338 us; speedup vs baseline: 15.0229x; 1.5810x over previous
//
#include <hip/hip_runtime.h>
#include <stdint.h>

typedef __bf16 bf16x8 __attribute__((ext_vector_type(8)));
typedef float f32x4 __attribute__((ext_vector_type(4)));

#define DEV __device__ __forceinline__
#define CAST_G(p) (const __attribute__((address_space(1))) unsigned int*)(p)
#define CAST_L(p) (__attribute__((address_space(3))) unsigned int*)(p)

constexpr int SEQ = 2048;
constexpr int DIM = 2048;
constexpr int NH  = 16;
constexpr int DK  = 128;
constexpr int BATCH = 2;
constexpr size_t TSZ = (size_t)BATCH * SEQ * DIM;   // 8388608 elements
constexpr size_t WSZ = (size_t)DIM * DIM;           // 4194304 elements per weight
constexpr float ATTN_SCALE = 0.08838834764831845f;  // 1/sqrt(128)

DEV unsigned short f2bf(float f) {
  unsigned int u = __float_as_uint(f);
  unsigned int r = (u + 0x7fffu + ((u >> 16) & 1u)) >> 16;
  return (unsigned short)r;
}

// ---------------------------------------------------------------------------
// fp32 -> bf16 (RTNE), 8 elements/thread, vectorized.
// ---------------------------------------------------------------------------
__global__ __launch_bounds__(256)
void cvt_f32_bf16(const float* __restrict__ src, unsigned short* __restrict__ dst,
                  int n8) {
  int i = blockIdx.x * 256 + threadIdx.x;
  if (i >= n8) return;
  float4 a = *reinterpret_cast<const float4*>(src + (size_t)i * 8);
  float4 b = *reinterpret_cast<const float4*>(src + (size_t)i * 8 + 4);
  unsigned short o[8];
  o[0] = f2bf(a.x); o[1] = f2bf(a.y); o[2] = f2bf(a.z); o[3] = f2bf(a.w);
  o[4] = f2bf(b.x); o[5] = f2bf(b.y); o[6] = f2bf(b.z); o[7] = f2bf(b.w);
  *reinterpret_cast<uint4*>(dst + (size_t)i * 8) = *reinterpret_cast<const uint4*>(o);
}

// ---------------------------------------------------------------------------
// GEMM: C[M,Nc] = A[M,K] * W[Nc,K]^T   (row-major, bf16 in, fp32 acc)
// 128x128 tile, BK=64, 4 waves (2x2).  Staging via global_load_lds(16B) with
// PRE-SWIZZLED SOURCE (involution c8^=(r&7)); LDS dest linear; reads XOR'd.
// MODE 0: plain row-major f32 store to Df            (WO projection)
// MODE 1: RoPE -> scatter [B,H,S,DK] bf16 to Db      (Q)
// MODE 2: RoPE -> scatter f32 to Df AND bf16 to Db   (K)
// MODE 3: scatter f32 to Df                          (V)
// ---------------------------------------------------------------------------
template <int MODE>
__global__ __launch_bounds__(256, 2)
void gemm_rope(const unsigned short* __restrict__ A,
               const unsigned short* __restrict__ W,
               unsigned short* __restrict__ Db,
               float* __restrict__ Df) {
  __shared__ __align__(16) unsigned short As[128 * 64];
  __shared__ __align__(16) unsigned short Bs[128 * 64];

  const int t = threadIdx.x;
  const int lane = t & 63;
  const int wid = t >> 6;
  const int wr = (wid >> 1) << 6;   // 0 / 64
  const int wc = (wid & 1) << 6;
  const int l16 = lane & 15, lg = lane >> 4;
  const int row0 = blockIdx.y * 128;
  const int col0 = blockIdx.x * 128;

  const int srow = t >> 3;                         // 0..31
  const int scol = ((t & 7) ^ (srow & 7)) << 3;    // pre-swizzled src elem off
  const unsigned short* Asrc = A + (size_t)(row0 + srow) * DIM + scol;
  const unsigned short* Wsrc = W + (size_t)(col0 + srow) * DIM + scol;

  f32x4 acc[4][4] = {};

  for (int k0 = 0; k0 < DIM; k0 += 64) {
    __syncthreads();
#pragma unroll
    for (int i = 0; i < 4; ++i) {
      __builtin_amdgcn_global_load_lds(CAST_G(Asrc + (size_t)i * 32 * DIM + k0),
                                       CAST_L(As + i * 2048 + wid * 512), 16, 0, 0);
      __builtin_amdgcn_global_load_lds(CAST_G(Wsrc + (size_t)i * 32 * DIM + k0),
                                       CAST_L(Bs + i * 2048 + wid * 512), 16, 0, 0);
    }
    __syncthreads();
#pragma unroll
    for (int ks = 0; ks < 2; ++ks) {
      bf16x8 af[4], bfr[4];
#pragma unroll
      for (int i = 0; i < 4; ++i) {
        int ra = wr + i * 16 + l16;
        af[i] = *reinterpret_cast<const bf16x8*>(&As[ra * 64 + (((ks * 4 + lg) ^ (ra & 7)) << 3)]);
        int rb = wc + i * 16 + l16;
        bfr[i] = *reinterpret_cast<const bf16x8*>(&Bs[rb * 64 + (((ks * 4 + lg) ^ (rb & 7)) << 3)]);
      }
#pragma unroll
      for (int i = 0; i < 4; ++i)
#pragma unroll
        for (int j = 0; j < 4; ++j)
          acc[i][j] = __builtin_amdgcn_mfma_f32_16x16x32_bf16(af[i], bfr[j], acc[i][j], 0, 0, 0);
    }
  }

  if (MODE == 0) {
#pragma unroll
    for (int i = 0; i < 4; ++i)
#pragma unroll
      for (int j = 0; j < 4; ++j) {
        int colg = col0 + wc + j * 16 + l16;
#pragma unroll
        for (int r = 0; r < 4; ++r) {
          int rowg = row0 + wr + i * 16 + lg * 4 + r;
          Df[(size_t)rowg * DIM + colg] = acc[i][j][r];
        }
      }
  } else {
#pragma unroll
    for (int j = 0; j < 4; ++j) {
      int colg = col0 + wc + j * 16 + l16;
      int jj = (colg >> 1) & 63;
      float invf = __expf((float)jj * -0.14391156831212787f);  // 10000^(-jj/64)
#pragma unroll
      for (int i = 0; i < 4; ++i) {
#pragma unroll
        for (int r = 0; r < 4; ++r) {
          int rowg = row0 + wr + i * 16 + lg * 4 + r;
          float v = acc[i][j][r];
          float outv;
          if (MODE == 1 || MODE == 2) {
            float p = __shfl_xor(v, 1, 64);
            int pos = rowg & (SEQ - 1);
            float ang = (float)pos * invf;
            float sn, cs;
            __sincosf(ang, &sn, &cs);
            outv = (colg & 1) ? fmaf(p, sn, v * cs) : fmaf(v, cs, -(p * sn));
          } else {
            outv = v;
          }
          int b = rowg >> 11, pos = rowg & (SEQ - 1);
          int h = colg >> 7, d = colg & (DK - 1);
          size_t idx = (((size_t)(b * NH + h)) * SEQ + pos) * DK + d;
          if (MODE == 1) Db[idx] = f2bf(outv);
          if (MODE == 2) { Df[idx] = outv; Db[idx] = f2bf(outv); }
          if (MODE == 3) Df[idx] = outv;
        }
      }
    }
  }
}

// ---------------------------------------------------------------------------
// V^T builder: V [B,H,S,DK] f32 -> VT [B,H,DK,S] bf16
// ---------------------------------------------------------------------------
__global__ __launch_bounds__(256, 2)
void vtrans(const float* __restrict__ V, unsigned short* __restrict__ VT) {
  __shared__ float vs[64 * 128];  // 32KB [pos][d]
  const int t = threadIdx.x;
  const int bh = blockIdx.y;
  const int p0 = blockIdx.x * 64;
  const float* src = V + ((size_t)bh * SEQ + p0) * DK;
#pragma unroll
  for (int s = 0; s < 8; ++s) {
    int id = s * 256 + t;
    *reinterpret_cast<float4*>(&vs[id * 4]) = *reinterpret_cast<const float4*>(&src[id * 4]);
  }
  __syncthreads();
  const int w = t >> 6, l = t & 63;
  unsigned short* dstb = VT + (size_t)bh * DK * SEQ + p0;
#pragma unroll
  for (int it = 0; it < 4; ++it) {
    int d = w * 32 + (it & 1) * 16 + (l & 15);
    int kc = (it >> 1) * 4 + (l >> 4);
    unsigned short tmp[8];
#pragma unroll
    for (int j = 0; j < 8; ++j) tmp[j] = f2bf(vs[(kc * 8 + j) * DK + d]);
    *reinterpret_cast<uint4*>(&dstb[(size_t)d * SEQ + kc * 8]) =
        *reinterpret_cast<const uint4*>(tmp);
  }
}

// ---------------------------------------------------------------------------
// Fused causal flash attention — ROUND-7 STRUCTURE (measured 222us) +
// vectorized LDS-transpose epilogue + bijective XCD-chunked swizzle.
// Q [B,H,S,DK] bf16 (roped, staged in LDS), K bf16, VT [B,H,DK,S] bf16
// -> AO [B*S, DIM] bf16.  256 thr / 4 waves; Q-tile 128; KV-tile 64.
// ---------------------------------------------------------------------------
struct __align__(16) AttnSmem {
  unsigned short Qs[128 * 128];   // 32KB  [q][dk], swizzled
  unsigned short Ks[64 * 128];    // 16KB  [key][dk], swizzled
  unsigned short Vts[128 * 64];   // 16KB  [d][key], swizzled
  unsigned short Ps[4 * 32 * 64]; // 16KB  per-wave P [q][key]; epilogue reuse
};

__global__ __launch_bounds__(256, 2)
void attn_fused(const unsigned short* __restrict__ Q,
                const unsigned short* __restrict__ K,
                const unsigned short* __restrict__ VT,
                unsigned short* __restrict__ AO) {
  __shared__ AttnSmem sm;
  const int t = threadIdx.x;
  const int lane = t & 63;
  const int wid = t >> 6;
  const int l16 = lane & 15, lg = lane >> 4;

  // XCD-chunked bijective swizzle: 64 blocks (4 bh x 16 qt) per XCD slot.
  const int lin = (int)(blockIdx.x + gridDim.x * blockIdx.y);  // 0..511
  const int xcd = lin & 7;
  const int idx = lin >> 3;                 // 0..63
  const int bh = xcd * 4 + (idx >> 4);      // 4 heads per XCD
  const int qt = 15 - (idx & 15);           // heavy tiles first
  const int b = bh >> 4, h = bh & 15;
  const int q0 = qt * 128;

  const unsigned short* Qbase = Q + ((size_t)bh * SEQ + q0) * DK;
  const unsigned short* Kbase = K + (size_t)bh * SEQ * DK;
  const unsigned short* VTbase = VT + (size_t)bh * DK * SEQ;

  // stage Q tile [128][128]: 256B rows -> 16 chunks, swizzle c^(r&7)
#pragma unroll
  for (int s = 0; s < 8; ++s) {
    int id = s * 256 + t;
    int r = id >> 4, c = id & 15;
    uint4 v = *reinterpret_cast<const uint4*>(Qbase + (size_t)r * DK + (c << 3));
    *reinterpret_cast<uint4*>(&sm.Qs[r * 128 + ((c ^ (r & 7)) << 3)]) = v;
  }

  f32x4 accO[2][8] = {};
  float mrun[2][4], lrun[2][4];
#pragma unroll
  for (int mi = 0; mi < 2; ++mi)
#pragma unroll
    for (int r = 0; r < 4; ++r) { mrun[mi][r] = -INFINITY; lrun[mi][r] = 0.f; }

  const int nkv = (q0 + 128) / 64;

  uint4 pk[4], pv[4];
#pragma unroll
  for (int s = 0; s < 4; ++s) {
    int id = s * 256 + t;
    int rk = id >> 4, ck = id & 15;
    pk[s] = *reinterpret_cast<const uint4*>(Kbase + (size_t)rk * DK + (ck << 3));
    int rv = id >> 3, cv = id & 7;
    pv[s] = *reinterpret_cast<const uint4*>(VTbase + (size_t)rv * SEQ + (cv << 3));
  }

  for (int kt = 0; kt < nkv; ++kt) {
    const int key0 = kt * 64;
    __syncthreads();
#pragma unroll
    for (int s = 0; s < 4; ++s) {
      int id = s * 256 + t;
      int rk = id >> 4, ck = id & 15;
      *reinterpret_cast<uint4*>(&sm.Ks[rk * 128 + ((ck ^ (rk & 7)) << 3)]) = pk[s];
      int rv = id >> 3, cv = id & 7;
      *reinterpret_cast<uint4*>(&sm.Vts[rv * 64 + ((cv ^ (rv & 7)) << 3)]) = pv[s];
    }
    __syncthreads();
    if (kt + 1 < nkv) {
      const int kn = key0 + 64;
#pragma unroll
      for (int s = 0; s < 4; ++s) {
        int id = s * 256 + t;
        int rk = id >> 4, ck = id & 15;
        pk[s] = *reinterpret_cast<const uint4*>(Kbase + (size_t)(kn + rk) * DK + (ck << 3));
        int rv = id >> 3, cv = id & 7;
        pv[s] = *reinterpret_cast<const uint4*>(VTbase + (size_t)rv * SEQ + kn + (cv << 3));
      }
    }

    // ---- S = Q K^T -------------------------------------------------------
    f32x4 sf[2][4] = {};
#pragma unroll
    for (int ks = 0; ks < 4; ++ks) {
      bf16x8 aq[2], bk[4];
#pragma unroll
      for (int mi = 0; mi < 2; ++mi) {
        int r = wid * 32 + mi * 16 + l16;
        aq[mi] = *reinterpret_cast<const bf16x8*>(
            &sm.Qs[r * 128 + (((ks * 4 + lg) ^ (r & 7)) << 3)]);
      }
#pragma unroll
      for (int nj = 0; nj < 4; ++nj) {
        int r = nj * 16 + l16;
        bk[nj] = *reinterpret_cast<const bf16x8*>(
            &sm.Ks[r * 128 + (((ks * 4 + lg) ^ (r & 7)) << 3)]);
      }
#pragma unroll
      for (int mi = 0; mi < 2; ++mi)
#pragma unroll
        for (int nj = 0; nj < 4; ++nj)
          sf[mi][nj] = __builtin_amdgcn_mfma_f32_16x16x32_bf16(aq[mi], bk[nj], sf[mi][nj], 0, 0, 0);
    }

    // ---- scale + causal mask --------------------------------------------
    const int qwbase = q0 + wid * 32;
    const bool need_mask = (key0 + 63) > qwbase;
#pragma unroll
    for (int mi = 0; mi < 2; ++mi)
#pragma unroll
      for (int nj = 0; nj < 4; ++nj) {
        int kcol = key0 + nj * 16 + l16;
#pragma unroll
        for (int r = 0; r < 4; ++r) {
          float v = sf[mi][nj][r] * ATTN_SCALE;
          if (need_mask) {
            int qrow = qwbase + mi * 16 + lg * 4 + r;
            if (kcol > qrow) v = -INFINITY;
          }
          sf[mi][nj][r] = v;
        }
      }

    // ---- online softmax --------------------------------------------------
#pragma unroll
    for (int mi = 0; mi < 2; ++mi) {
      float alpha[4];
#pragma unroll
      for (int r = 0; r < 4; ++r) {
        float m0 = fmaxf(fmaxf(sf[mi][0][r], sf[mi][1][r]),
                         fmaxf(sf[mi][2][r], sf[mi][3][r]));
#pragma unroll
        for (int off = 1; off < 16; off <<= 1)
          m0 = fmaxf(m0, __shfl_xor(m0, off, 64));
        float mn = fmaxf(mrun[mi][r], m0);
        alpha[r] = __expf(mrun[mi][r] - mn);   // exp(-inf)=0 on first tile
        mrun[mi][r] = mn;
      }
      float rs[4] = {0.f, 0.f, 0.f, 0.f};
#pragma unroll
      for (int nj = 0; nj < 4; ++nj) {
        int colb = nj * 16 + l16;
        int ch = colb >> 3, cb = colb & 7;
#pragma unroll
        for (int r = 0; r < 4; ++r) {
          float p = __expf(sf[mi][nj][r] - mrun[mi][r]);
          rs[r] += p;
          int prow = mi * 16 + lg * 4 + r;
          sm.Ps[wid * 2048 + prow * 64 + ((ch ^ (prow & 7)) << 3) + cb] = f2bf(p);
        }
      }
#pragma unroll
      for (int r = 0; r < 4; ++r) {
        float s0 = rs[r];
#pragma unroll
        for (int off = 1; off < 16; off <<= 1)
          s0 += __shfl_xor(s0, off, 64);
        lrun[mi][r] = lrun[mi][r] * alpha[r] + s0;
      }
#pragma unroll
      for (int dj = 0; dj < 8; ++dj)
#pragma unroll
        for (int r = 0; r < 4; ++r) accO[mi][dj][r] *= alpha[r];
    }

    // ---- PV --------------------------------------------------------------
#pragma unroll
    for (int ks = 0; ks < 2; ++ks) {
      bf16x8 ap[2], bv[8];
#pragma unroll
      for (int mi = 0; mi < 2; ++mi) {
        int r = mi * 16 + l16;
        ap[mi] = *reinterpret_cast<const bf16x8*>(
            &sm.Ps[wid * 2048 + r * 64 + (((ks * 4 + lg) ^ (r & 7)) << 3)]);
      }
#pragma unroll
      for (int dj = 0; dj < 8; ++dj) {
        int r = dj * 16 + l16;
        bv[dj] = *reinterpret_cast<const bf16x8*>(
            &sm.Vts[r * 64 + (((ks * 4 + lg) ^ (r & 7)) << 3)]);
      }
#pragma unroll
      for (int mi = 0; mi < 2; ++mi)
#pragma unroll
        for (int dj = 0; dj < 8; ++dj)
          accO[mi][dj] = __builtin_amdgcn_mfma_f32_16x16x32_bf16(ap[mi], bv[dj], accO[mi][dj], 0, 0, 0);
    }
  }

  // ---- epilogue: per-wave LDS transpose -> contiguous uint4 stores -------
  unsigned short* Pw = &sm.Ps[wid * 2048];  // 16x128 tile per pass
#pragma unroll
  for (int mi = 0; mi < 2; ++mi) {
    float inv[4];
#pragma unroll
    for (int r = 0; r < 4; ++r) inv[r] = 1.0f / lrun[mi][r];
#pragma unroll
    for (int dj = 0; dj < 8; ++dj)
#pragma unroll
      for (int r = 0; r < 4; ++r)
        Pw[(lg * 4 + r) * 128 + dj * 16 + l16] = f2bf(accO[mi][dj][r] * inv[r]);
    // same-wave write->read; compiler inserts lgkmcnt
#pragma unroll
    for (int ps = 0; ps < 4; ++ps) {
      int row = ps * 4 + lg;               // 0..15
      uint4 v = *reinterpret_cast<const uint4*>(&Pw[row * 128 + l16 * 8]);
      int qpos = q0 + wid * 32 + mi * 16 + row;
      *reinterpret_cast<uint4*>(
          &AO[((size_t)(b * SEQ + qpos)) * DIM + h * DK + l16 * 8]) = v;
    }
  }
}

// ---------------------------------------------------------------------------
extern "C" void kernel_launch(void* const* d_in, const int* in_sizes, int n_in,
                              void* d_out, int out_size, void* d_ws, size_t ws_size,
                              hipStream_t stream) {
  const float* x  = (const float*)d_in[0];
  const float* wq = (const float*)d_in[1];
  const float* wk = (const float*)d_in[2];
  const float* wv = (const float*)d_in[3];
  const float* wo = (const float*)d_in[4];

  // Outputs are FLOAT32: out [B,S,DIM], K [B,H,S,DK], V [B,H,S,DK].
  float* outF = (float*)d_out;
  float* outK = outF + TSZ;
  float* outV = outF + 2 * TSZ;

  // bf16 Q/K copies live in the (dead until final GEMM) out[0] f32 slot.
  unsigned short* qb = (unsigned short*)outF;
  unsigned short* kb = qb + TSZ;

  // ws (bf16 elems), total 2*TSZ + WSZ = 41.9 MB (proven footprint):
  unsigned short* xb  = (unsigned short*)d_ws;  // converted x; later VT
  unsigned short* aop = xb + TSZ;               // AO (attn output staging)
  unsigned short* wb  = xb + 2 * TSZ;           // jit-converted weight
  unsigned short* vtb = xb;                     // VT over xb (x dead post-QKV)

  dim3 blk(256);
  dim3 ggrid(16, 32);
  const int cvtW = (int)(WSZ / 2048), n8W = (int)(WSZ / 8);

  cvt_f32_bf16<<<dim3((int)(TSZ / 2048)), blk, 0, stream>>>(x, xb, (int)(TSZ / 8));

  cvt_f32_bf16<<<dim3(cvtW), blk, 0, stream>>>(wq, wb, n8W);
  gemm_rope<1><<<ggrid, blk, 0, stream>>>(xb, wb, qb, nullptr);       // Q bf16

  cvt_f32_bf16<<<dim3(cvtW), blk, 0, stream>>>(wk, wb, n8W);
  gemm_rope<2><<<ggrid, blk, 0, stream>>>(xb, wb, kb, outK);          // K f32+bf16

  cvt_f32_bf16<<<dim3(cvtW), blk, 0, stream>>>(wv, wb, n8W);
  gemm_rope<3><<<ggrid, blk, 0, stream>>>(xb, wb, nullptr, outV);     // V f32

  vtrans<<<dim3(32, 32), blk, 0, stream>>>(outV, vtb);                // VT bf16

  attn_fused<<<dim3(16, 32), blk, 0, stream>>>(qb, kb, vtb, aop);

  cvt_f32_bf16<<<dim3(cvtW), blk, 0, stream>>>(wo, wb, n8W);
  gemm_rope<0><<<ggrid, blk, 0, stream>>>(aop, wb, nullptr, outF);    // final f32
}

// Round 11
// 358.320 us; speedup vs baseline: 16.6588x; 1.1089x over previous
//
#include <hip/hip_runtime.h>
#include <stdint.h>

typedef __bf16 bf16x8 __attribute__((ext_vector_type(8)));
typedef float f32x4 __attribute__((ext_vector_type(4)));

#define DEV __device__ __forceinline__
#define CAST_G(p) (const __attribute__((address_space(1))) unsigned int*)(p)
#define CAST_L(p) (__attribute__((address_space(3))) unsigned int*)(p)

constexpr int SEQ = 2048;
constexpr int DIM = 2048;
constexpr int NH  = 16;
constexpr int DK  = 128;
constexpr int BATCH = 2;
constexpr size_t TSZ = (size_t)BATCH * SEQ * DIM;   // 8388608 elements
constexpr size_t WSZ = (size_t)DIM * DIM;           // 4194304 elements per weight
constexpr float ATTN_SCALE = 0.08838834764831845f;  // 1/sqrt(128)

DEV unsigned short f2bf(float f) {
  unsigned int u = __float_as_uint(f);
  unsigned int r = (u + 0x7fffu + ((u >> 16) & 1u)) >> 16;
  return (unsigned short)r;
}

// ---------------------------------------------------------------------------
// fp32 -> bf16 (RTNE), 8 elements/thread, vectorized.
// ---------------------------------------------------------------------------
__global__ __launch_bounds__(256)
void cvt_f32_bf16(const float* __restrict__ src, unsigned short* __restrict__ dst,
                  int n8) {
  int i = blockIdx.x * 256 + threadIdx.x;
  if (i >= n8) return;
  float4 a = *reinterpret_cast<const float4*>(src + (size_t)i * 8);
  float4 b = *reinterpret_cast<const float4*>(src + (size_t)i * 8 + 4);
  unsigned short o[8];
  o[0] = f2bf(a.x); o[1] = f2bf(a.y); o[2] = f2bf(a.z); o[3] = f2bf(a.w);
  o[4] = f2bf(b.x); o[5] = f2bf(b.y); o[6] = f2bf(b.z); o[7] = f2bf(b.w);
  *reinterpret_cast<uint4*>(dst + (size_t)i * 8) = *reinterpret_cast<const uint4*>(o);
}

// ---------------------------------------------------------------------------
// GEMM: C[M,Nc] = A[M,K] * W[Nc,K]^T   (row-major, bf16 in, fp32 acc)
// 128x128 tile, BK=64, 4 waves (2x2).  Staging via global_load_lds(16B) with
// PRE-SWIZZLED SOURCE (involution c8^=(r&7)); LDS dest linear; reads XOR'd.
// MODE 0: plain row-major f32 store to Df            (WO projection)
// MODE 1: RoPE -> scatter [B,H,S,DK] bf16 to Db      (Q)
// MODE 2: RoPE -> scatter f32 to Df AND bf16 to Db   (K)
// MODE 3: scatter f32 to Df                          (V)
// ---------------------------------------------------------------------------
template <int MODE>
__global__ __launch_bounds__(256, 2)
void gemm_rope(const unsigned short* __restrict__ A,
               const unsigned short* __restrict__ W,
               unsigned short* __restrict__ Db,
               float* __restrict__ Df) {
  __shared__ __align__(16) unsigned short As[128 * 64];
  __shared__ __align__(16) unsigned short Bs[128 * 64];

  const int t = threadIdx.x;
  const int lane = t & 63;
  const int wid = t >> 6;
  const int wr = (wid >> 1) << 6;   // 0 / 64
  const int wc = (wid & 1) << 6;
  const int l16 = lane & 15, lg = lane >> 4;
  const int row0 = blockIdx.y * 128;
  const int col0 = blockIdx.x * 128;

  const int srow = t >> 3;                         // 0..31
  const int scol = ((t & 7) ^ (srow & 7)) << 3;    // pre-swizzled src elem off
  const unsigned short* Asrc = A + (size_t)(row0 + srow) * DIM + scol;
  const unsigned short* Wsrc = W + (size_t)(col0 + srow) * DIM + scol;

  f32x4 acc[4][4] = {};

  for (int k0 = 0; k0 < DIM; k0 += 64) {
    __syncthreads();
#pragma unroll
    for (int i = 0; i < 4; ++i) {
      __builtin_amdgcn_global_load_lds(CAST_G(Asrc + (size_t)i * 32 * DIM + k0),
                                       CAST_L(As + i * 2048 + wid * 512), 16, 0, 0);
      __builtin_amdgcn_global_load_lds(CAST_G(Wsrc + (size_t)i * 32 * DIM + k0),
                                       CAST_L(Bs + i * 2048 + wid * 512), 16, 0, 0);
    }
    __syncthreads();
#pragma unroll
    for (int ks = 0; ks < 2; ++ks) {
      bf16x8 af[4], bfr[4];
#pragma unroll
      for (int i = 0; i < 4; ++i) {
        int ra = wr + i * 16 + l16;
        af[i] = *reinterpret_cast<const bf16x8*>(&As[ra * 64 + (((ks * 4 + lg) ^ (ra & 7)) << 3)]);
        int rb = wc + i * 16 + l16;
        bfr[i] = *reinterpret_cast<const bf16x8*>(&Bs[rb * 64 + (((ks * 4 + lg) ^ (rb & 7)) << 3)]);
      }
#pragma unroll
      for (int i = 0; i < 4; ++i)
#pragma unroll
        for (int j = 0; j < 4; ++j)
          acc[i][j] = __builtin_amdgcn_mfma_f32_16x16x32_bf16(af[i], bfr[j], acc[i][j], 0, 0, 0);
    }
  }

  if (MODE == 0) {
#pragma unroll
    for (int i = 0; i < 4; ++i)
#pragma unroll
      for (int j = 0; j < 4; ++j) {
        int colg = col0 + wc + j * 16 + l16;
#pragma unroll
        for (int r = 0; r < 4; ++r) {
          int rowg = row0 + wr + i * 16 + lg * 4 + r;
          Df[(size_t)rowg * DIM + colg] = acc[i][j][r];
        }
      }
  } else {
#pragma unroll
    for (int j = 0; j < 4; ++j) {
      int colg = col0 + wc + j * 16 + l16;
      int jj = (colg >> 1) & 63;
      float invf = __expf((float)jj * -0.14391156831212787f);  // 10000^(-jj/64)
#pragma unroll
      for (int i = 0; i < 4; ++i) {
#pragma unroll
        for (int r = 0; r < 4; ++r) {
          int rowg = row0 + wr + i * 16 + lg * 4 + r;
          float v = acc[i][j][r];
          float outv;
          if (MODE == 1 || MODE == 2) {
            float p = __shfl_xor(v, 1, 64);
            int pos = rowg & (SEQ - 1);
            float ang = (float)pos * invf;
            float sn, cs;
            __sincosf(ang, &sn, &cs);
            outv = (colg & 1) ? fmaf(p, sn, v * cs) : fmaf(v, cs, -(p * sn));
          } else {
            outv = v;
          }
          int b = rowg >> 11, pos = rowg & (SEQ - 1);
          int h = colg >> 7, d = colg & (DK - 1);
          size_t idx = (((size_t)(b * NH + h)) * SEQ + pos) * DK + d;
          if (MODE == 1) Db[idx] = f2bf(outv);
          if (MODE == 2) { Df[idx] = outv; Db[idx] = f2bf(outv); }
          if (MODE == 3) Df[idx] = outv;
        }
      }
    }
  }
}

// ---------------------------------------------------------------------------
// V^T builder: V [B,H,S,DK] f32 -> VT [B,H,DK,S] bf16
// ---------------------------------------------------------------------------
__global__ __launch_bounds__(256, 2)
void vtrans(const float* __restrict__ V, unsigned short* __restrict__ VT) {
  __shared__ float vs[64 * 128];  // 32KB [pos][d]
  const int t = threadIdx.x;
  const int bh = blockIdx.y;
  const int p0 = blockIdx.x * 64;
  const float* src = V + ((size_t)bh * SEQ + p0) * DK;
#pragma unroll
  for (int s = 0; s < 8; ++s) {
    int id = s * 256 + t;
    *reinterpret_cast<float4*>(&vs[id * 4]) = *reinterpret_cast<const float4*>(&src[id * 4]);
  }
  __syncthreads();
  const int w = t >> 6, l = t & 63;
  unsigned short* dstb = VT + (size_t)bh * DK * SEQ + p0;
#pragma unroll
  for (int it = 0; it < 4; ++it) {
    int d = w * 32 + (it & 1) * 16 + (l & 15);
    int kc = (it >> 1) * 4 + (l >> 4);
    unsigned short tmp[8];
#pragma unroll
    for (int j = 0; j < 8; ++j) tmp[j] = f2bf(vs[(kc * 8 + j) * DK + d]);
    *reinterpret_cast<uint4*>(&dstb[(size_t)d * SEQ + kc * 8]) =
        *reinterpret_cast<const uint4*>(tmp);
  }
}

// ---------------------------------------------------------------------------
// Fused causal flash attention — 512 thr / 8 waves, one block per (pair, bh).
// Each block processes q-tiles {15-j, j}: 2(16-j)+2(j+1) = 34 kv-iters for
// EVERY block (perfect causal load balance).  Each wave owns 16 q-rows.
// Q [B,H,S,DK] bf16 (roped, staged in LDS), K bf16, VT [B,H,DK,S] bf16
// -> AO [B*S, DIM] bf16.  KV-tile 64.  LDS 80KB; 8 waves/CU = 2/SIMD.
// ---------------------------------------------------------------------------
struct __align__(16) AttnSmem {
  unsigned short Qs[128 * 128];   // 32KB  [q][dk], swizzled
  unsigned short Ks[64 * 128];    // 16KB  [key][dk], swizzled   (epilogue reuse)
  unsigned short Vts[128 * 64];   // 16KB  [d][key], swizzled    (epilogue reuse)
  unsigned short Ps[8 * 16 * 64]; // 16KB  per-wave P [16 q][64 key], swizzled
};

__global__ __launch_bounds__(512, 1)
void attn_fused(const unsigned short* __restrict__ Q,
                const unsigned short* __restrict__ K,
                const unsigned short* __restrict__ VT,
                unsigned short* __restrict__ AO) {
  __shared__ AttnSmem sm;
  const int t = threadIdx.x;          // 0..511
  const int lane = t & 63;
  const int wid = t >> 6;             // 0..7
  const int l16 = lane & 15, lg = lane >> 4;
  const int pj = blockIdx.x;          // 0..7 pair id
  const int bh = blockIdx.y;
  const int b = bh >> 4, h = bh & 15;

  const unsigned short* Kbase = K + (size_t)bh * SEQ * DK;
  const unsigned short* VTbase = VT + (size_t)bh * DK * SEQ;

  for (int half = 0; half < 2; ++half) {
    const int qt = half ? pj : (15 - pj);
    const int q0 = qt * 128;
    const int nkv = 2 * (qt + 1);
    const unsigned short* Qbase = Q + ((size_t)bh * SEQ + q0) * DK;

    // stage Q tile [128][128]: 16 chunks/row, swizzle c^(r&7)
#pragma unroll
    for (int s = 0; s < 4; ++s) {
      int id = s * 512 + t;
      int r = id >> 4, c = id & 15;
      uint4 v = *reinterpret_cast<const uint4*>(Qbase + (size_t)r * DK + (c << 3));
      *reinterpret_cast<uint4*>(&sm.Qs[r * 128 + ((c ^ (r & 7)) << 3)]) = v;
    }

    f32x4 accO[8] = {};
    float mrun[4], lrun[4];
#pragma unroll
    for (int r = 0; r < 4; ++r) { mrun[r] = -INFINITY; lrun[r] = 0.f; }

    uint4 pk[2], pv[2];
#pragma unroll
    for (int s = 0; s < 2; ++s) {
      int id = s * 512 + t;
      int rk = id >> 4, ck = id & 15;
      pk[s] = *reinterpret_cast<const uint4*>(Kbase + (size_t)rk * DK + (ck << 3));
      int rv = id >> 3, cv = id & 7;
      pv[s] = *reinterpret_cast<const uint4*>(VTbase + (size_t)rv * SEQ + (cv << 3));
    }

    for (int kt = 0; kt < nkv; ++kt) {
      const int key0 = kt * 64;
      __syncthreads();
#pragma unroll
      for (int s = 0; s < 2; ++s) {
        int id = s * 512 + t;
        int rk = id >> 4, ck = id & 15;
        *reinterpret_cast<uint4*>(&sm.Ks[rk * 128 + ((ck ^ (rk & 7)) << 3)]) = pk[s];
        int rv = id >> 3, cv = id & 7;
        *reinterpret_cast<uint4*>(&sm.Vts[rv * 64 + ((cv ^ (rv & 7)) << 3)]) = pv[s];
      }
      __syncthreads();
      if (kt + 1 < nkv) {
        const int kn = key0 + 64;
#pragma unroll
        for (int s = 0; s < 2; ++s) {
          int id = s * 512 + t;
          int rk = id >> 4, ck = id & 15;
          pk[s] = *reinterpret_cast<const uint4*>(Kbase + (size_t)(kn + rk) * DK + (ck << 3));
          int rv = id >> 3, cv = id & 7;
          pv[s] = *reinterpret_cast<const uint4*>(VTbase + (size_t)rv * SEQ + kn + (cv << 3));
        }
      }

      // ---- S = Q K^T  (16 q-rows per wave) ------------------------------
      f32x4 sf[4] = {};
#pragma unroll
      for (int ks = 0; ks < 4; ++ks) {
        int ra = wid * 16 + l16;
        bf16x8 aq = *reinterpret_cast<const bf16x8*>(
            &sm.Qs[ra * 128 + (((ks * 4 + lg) ^ (ra & 7)) << 3)]);
#pragma unroll
        for (int nj = 0; nj < 4; ++nj) {
          int rb = nj * 16 + l16;
          bf16x8 bk = *reinterpret_cast<const bf16x8*>(
              &sm.Ks[rb * 128 + (((ks * 4 + lg) ^ (rb & 7)) << 3)]);
          sf[nj] = __builtin_amdgcn_mfma_f32_16x16x32_bf16(aq, bk, sf[nj], 0, 0, 0);
        }
      }

      // ---- scale + causal mask ------------------------------------------
      const int qwbase = q0 + wid * 16;
      const bool need_mask = (key0 + 63) > qwbase;
#pragma unroll
      for (int nj = 0; nj < 4; ++nj) {
        int kcol = key0 + nj * 16 + l16;
#pragma unroll
        for (int r = 0; r < 4; ++r) {
          float v = sf[nj][r] * ATTN_SCALE;
          if (need_mask) {
            int qrow = qwbase + lg * 4 + r;
            if (kcol > qrow) v = -INFINITY;
          }
          sf[nj][r] = v;
        }
      }

      // ---- online softmax -----------------------------------------------
      float alpha[4];
#pragma unroll
      for (int r = 0; r < 4; ++r) {
        float m0 = fmaxf(fmaxf(sf[0][r], sf[1][r]), fmaxf(sf[2][r], sf[3][r]));
#pragma unroll
        for (int off = 1; off < 16; off <<= 1)
          m0 = fmaxf(m0, __shfl_xor(m0, off, 64));
        float mn = fmaxf(mrun[r], m0);
        alpha[r] = __expf(mrun[r] - mn);   // exp(-inf)=0 on first tile
        mrun[r] = mn;
      }
      float rs[4] = {0.f, 0.f, 0.f, 0.f};
#pragma unroll
      for (int nj = 0; nj < 4; ++nj) {
        int colb = nj * 16 + l16;
        int ch = colb >> 3, cb = colb & 7;
#pragma unroll
        for (int r = 0; r < 4; ++r) {
          float p = __expf(sf[nj][r] - mrun[r]);
          rs[r] += p;
          int prow = lg * 4 + r;
          sm.Ps[wid * 1024 + prow * 64 + ((ch ^ (prow & 7)) << 3) + cb] = f2bf(p);
        }
      }
#pragma unroll
      for (int r = 0; r < 4; ++r) {
        float s0 = rs[r];
#pragma unroll
        for (int off = 1; off < 16; off <<= 1)
          s0 += __shfl_xor(s0, off, 64);
        lrun[r] = lrun[r] * alpha[r] + s0;
      }
#pragma unroll
      for (int dj = 0; dj < 8; ++dj)
#pragma unroll
        for (int r = 0; r < 4; ++r) accO[dj][r] *= alpha[r];

      // ---- PV -----------------------------------------------------------
#pragma unroll
      for (int ks = 0; ks < 2; ++ks) {
        bf16x8 ap = *reinterpret_cast<const bf16x8*>(
            &sm.Ps[wid * 1024 + l16 * 64 + (((ks * 4 + lg) ^ (l16 & 7)) << 3)]);
#pragma unroll
        for (int dj = 0; dj < 8; ++dj) {
          int rv = dj * 16 + l16;
          bf16x8 bv = *reinterpret_cast<const bf16x8*>(
              &sm.Vts[rv * 64 + (((ks * 4 + lg) ^ (rv & 7)) << 3)]);
          accO[dj] = __builtin_amdgcn_mfma_f32_16x16x32_bf16(ap, bv, accO[dj], 0, 0, 0);
        }
      }
    }

    // ---- epilogue: reuse (dead) Ks/Vts as per-wave 16x128 transpose tile
    __syncthreads();   // all waves done reading Ks/Vts
    unsigned short* Pw = sm.Ks + wid * 2048;
    float inv[4];
#pragma unroll
    for (int r = 0; r < 4; ++r) inv[r] = 1.0f / lrun[r];
#pragma unroll
    for (int dj = 0; dj < 8; ++dj)
#pragma unroll
      for (int r = 0; r < 4; ++r)
        Pw[(lg * 4 + r) * 128 + dj * 16 + l16] = f2bf(accO[dj][r] * inv[r]);
    // same-wave write->read; compiler inserts lgkmcnt
#pragma unroll
    for (int ps = 0; ps < 4; ++ps) {
      int row = ps * 4 + lg;               // 0..15
      uint4 v = *reinterpret_cast<const uint4*>(&Pw[row * 128 + l16 * 8]);
      int qpos = q0 + wid * 16 + row;
      *reinterpret_cast<uint4*>(
          &AO[((size_t)(b * SEQ + qpos)) * DIM + h * DK + l16 * 8]) = v;
    }
    __syncthreads();   // protect Ks/Vts before next half restages
  }
}

// ---------------------------------------------------------------------------
extern "C" void kernel_launch(void* const* d_in, const int* in_sizes, int n_in,
                              void* d_out, int out_size, void* d_ws, size_t ws_size,
                              hipStream_t stream) {
  const float* x  = (const float*)d_in[0];
  const float* wq = (const float*)d_in[1];
  const float* wk = (const float*)d_in[2];
  const float* wv = (const float*)d_in[3];
  const float* wo = (const float*)d_in[4];

  // Outputs are FLOAT32: out [B,S,DIM], K [B,H,S,DK], V [B,H,S,DK].
  float* outF = (float*)d_out;
  float* outK = outF + TSZ;
  float* outV = outF + 2 * TSZ;

  // bf16 Q/K copies live in the (dead until final GEMM) out[0] f32 slot.
  unsigned short* qb = (unsigned short*)outF;
  unsigned short* kb = qb + TSZ;

  // ws (bf16 elems), total 2*TSZ + WSZ = 41.9 MB (proven footprint):
  unsigned short* xb  = (unsigned short*)d_ws;  // converted x; later VT
  unsigned short* aop = xb + TSZ;               // AO (attn output staging)
  unsigned short* wb  = xb + 2 * TSZ;           // jit-converted weight
  unsigned short* vtb = xb;                     // VT over xb (x dead post-QKV)

  dim3 blk(256);
  dim3 ggrid(16, 32);
  const int cvtW = (int)(WSZ / 2048), n8W = (int)(WSZ / 8);

  cvt_f32_bf16<<<dim3((int)(TSZ / 2048)), blk, 0, stream>>>(x, xb, (int)(TSZ / 8));

  cvt_f32_bf16<<<dim3(cvtW), blk, 0, stream>>>(wq, wb, n8W);
  gemm_rope<1><<<ggrid, blk, 0, stream>>>(xb, wb, qb, nullptr);       // Q bf16

  cvt_f32_bf16<<<dim3(cvtW), blk, 0, stream>>>(wk, wb, n8W);
  gemm_rope<2><<<ggrid, blk, 0, stream>>>(xb, wb, kb, outK);          // K f32+bf16

  cvt_f32_bf16<<<dim3(cvtW), blk, 0, stream>>>(wv, wb, n8W);
  gemm_rope<3><<<ggrid, blk, 0, stream>>>(xb, wb, nullptr, outV);     // V f32

  vtrans<<<dim3(32, 32), blk, 0, stream>>>(outV, vtb);                // VT bf16

  attn_fused<<<dim3(8, 32), dim3(512), 0, stream>>>(qb, kb, vtb, aop);

  cvt_f32_bf16<<<dim3(cvtW), blk, 0, stream>>>(wo, wb, n8W);
  gemm_rope<0><<<ggrid, blk, 0, stream>>>(aop, wb, nullptr, outF);    // final f32
}

// Round 12
// 329.087 us; speedup vs baseline: 18.1386x; 1.0888x over previous
//
#include <hip/hip_runtime.h>
#include <stdint.h>

typedef __bf16 bf16x8 __attribute__((ext_vector_type(8)));
typedef float f32x4 __attribute__((ext_vector_type(4)));

#define DEV __device__ __forceinline__
#define CAST_G(p) (const __attribute__((address_space(1))) unsigned int*)(p)
#define CAST_L(p) (__attribute__((address_space(3))) unsigned int*)(p)

constexpr int SEQ = 2048;
constexpr int DIM = 2048;
constexpr int NH  = 16;
constexpr int DK  = 128;
constexpr int BATCH = 2;
constexpr size_t TSZ = (size_t)BATCH * SEQ * DIM;   // 8388608 elements
constexpr size_t WSZ = (size_t)DIM * DIM;           // 4194304 elements per weight
constexpr float ATTN_SCALE = 0.08838834764831845f;  // 1/sqrt(128)

DEV unsigned short f2bf(float f) {
  unsigned int u = __float_as_uint(f);
  unsigned int r = (u + 0x7fffu + ((u >> 16) & 1u)) >> 16;
  return (unsigned short)r;
}

// ---------------------------------------------------------------------------
// fp32 -> bf16 (RTNE), 8 elements/thread, vectorized.
// ---------------------------------------------------------------------------
__global__ __launch_bounds__(256)
void cvt_f32_bf16(const float* __restrict__ src, unsigned short* __restrict__ dst,
                  int n8) {
  int i = blockIdx.x * 256 + threadIdx.x;
  if (i >= n8) return;
  float4 a = *reinterpret_cast<const float4*>(src + (size_t)i * 8);
  float4 b = *reinterpret_cast<const float4*>(src + (size_t)i * 8 + 4);
  unsigned short o[8];
  o[0] = f2bf(a.x); o[1] = f2bf(a.y); o[2] = f2bf(a.z); o[3] = f2bf(a.w);
  o[4] = f2bf(b.x); o[5] = f2bf(b.y); o[6] = f2bf(b.z); o[7] = f2bf(b.w);
  *reinterpret_cast<uint4*>(dst + (size_t)i * 8) = *reinterpret_cast<const uint4*>(o);
}

// ---------------------------------------------------------------------------
// GEMM: C[M,Nc] = A[M,K] * W[Nc,K]^T   (row-major, bf16 in, fp32 acc)
// 128x128 tile, BK=64, 4 waves (2x2).  Staging via global_load_lds(16B) with
// PRE-SWIZZLED SOURCE (involution c8^=(r&7)); LDS dest linear; reads XOR'd.
// MODE 0: plain row-major f32 store to Df            (WO projection)
// MODE 1: RoPE -> scatter [B,H,S,DK] bf16 to Db      (Q)
// MODE 2: RoPE -> scatter f32 to Df AND bf16 to Db   (K)
// MODE 3: scatter f32 to Df                          (V)
// ---------------------------------------------------------------------------
template <int MODE>
__global__ __launch_bounds__(256, 2)
void gemm_rope(const unsigned short* __restrict__ A,
               const unsigned short* __restrict__ W,
               unsigned short* __restrict__ Db,
               float* __restrict__ Df) {
  __shared__ __align__(16) unsigned short As[128 * 64];
  __shared__ __align__(16) unsigned short Bs[128 * 64];

  const int t = threadIdx.x;
  const int lane = t & 63;
  const int wid = t >> 6;
  const int wr = (wid >> 1) << 6;   // 0 / 64
  const int wc = (wid & 1) << 6;
  const int l16 = lane & 15, lg = lane >> 4;
  const int row0 = blockIdx.y * 128;
  const int col0 = blockIdx.x * 128;

  const int srow = t >> 3;                         // 0..31
  const int scol = ((t & 7) ^ (srow & 7)) << 3;    // pre-swizzled src elem off
  const unsigned short* Asrc = A + (size_t)(row0 + srow) * DIM + scol;
  const unsigned short* Wsrc = W + (size_t)(col0 + srow) * DIM + scol;

  f32x4 acc[4][4] = {};

  for (int k0 = 0; k0 < DIM; k0 += 64) {
    __syncthreads();
#pragma unroll
    for (int i = 0; i < 4; ++i) {
      __builtin_amdgcn_global_load_lds(CAST_G(Asrc + (size_t)i * 32 * DIM + k0),
                                       CAST_L(As + i * 2048 + wid * 512), 16, 0, 0);
      __builtin_amdgcn_global_load_lds(CAST_G(Wsrc + (size_t)i * 32 * DIM + k0),
                                       CAST_L(Bs + i * 2048 + wid * 512), 16, 0, 0);
    }
    __syncthreads();
#pragma unroll
    for (int ks = 0; ks < 2; ++ks) {
      bf16x8 af[4], bfr[4];
#pragma unroll
      for (int i = 0; i < 4; ++i) {
        int ra = wr + i * 16 + l16;
        af[i] = *reinterpret_cast<const bf16x8*>(&As[ra * 64 + (((ks * 4 + lg) ^ (ra & 7)) << 3)]);
        int rb = wc + i * 16 + l16;
        bfr[i] = *reinterpret_cast<const bf16x8*>(&Bs[rb * 64 + (((ks * 4 + lg) ^ (rb & 7)) << 3)]);
      }
#pragma unroll
      for (int i = 0; i < 4; ++i)
#pragma unroll
        for (int j = 0; j < 4; ++j)
          acc[i][j] = __builtin_amdgcn_mfma_f32_16x16x32_bf16(af[i], bfr[j], acc[i][j], 0, 0, 0);
    }
  }

  if (MODE == 0) {
#pragma unroll
    for (int i = 0; i < 4; ++i)
#pragma unroll
      for (int j = 0; j < 4; ++j) {
        int colg = col0 + wc + j * 16 + l16;
#pragma unroll
        for (int r = 0; r < 4; ++r) {
          int rowg = row0 + wr + i * 16 + lg * 4 + r;
          Df[(size_t)rowg * DIM + colg] = acc[i][j][r];
        }
      }
  } else {
#pragma unroll
    for (int j = 0; j < 4; ++j) {
      int colg = col0 + wc + j * 16 + l16;
      int jj = (colg >> 1) & 63;
      float invf = __expf((float)jj * -0.14391156831212787f);  // 10000^(-jj/64)
#pragma unroll
      for (int i = 0; i < 4; ++i) {
#pragma unroll
        for (int r = 0; r < 4; ++r) {
          int rowg = row0 + wr + i * 16 + lg * 4 + r;
          float v = acc[i][j][r];
          float outv;
          if (MODE == 1 || MODE == 2) {
            float p = __shfl_xor(v, 1, 64);
            int pos = rowg & (SEQ - 1);
            float ang = (float)pos * invf;
            float sn, cs;
            __sincosf(ang, &sn, &cs);
            outv = (colg & 1) ? fmaf(p, sn, v * cs) : fmaf(v, cs, -(p * sn));
          } else {
            outv = v;
          }
          int b = rowg >> 11, pos = rowg & (SEQ - 1);
          int h = colg >> 7, d = colg & (DK - 1);
          size_t idx = (((size_t)(b * NH + h)) * SEQ + pos) * DK + d;
          if (MODE == 1) Db[idx] = f2bf(outv);
          if (MODE == 2) { Df[idx] = outv; Db[idx] = f2bf(outv); }
          if (MODE == 3) Df[idx] = outv;
        }
      }
    }
  }
}

// ---------------------------------------------------------------------------
// V^T builder: V [B,H,S,DK] f32 -> VT [B,H,DK,S] bf16
// ---------------------------------------------------------------------------
__global__ __launch_bounds__(256, 2)
void vtrans(const float* __restrict__ V, unsigned short* __restrict__ VT) {
  __shared__ float vs[64 * 128];  // 32KB [pos][d]
  const int t = threadIdx.x;
  const int bh = blockIdx.y;
  const int p0 = blockIdx.x * 64;
  const float* src = V + ((size_t)bh * SEQ + p0) * DK;
#pragma unroll
  for (int s = 0; s < 8; ++s) {
    int id = s * 256 + t;
    *reinterpret_cast<float4*>(&vs[id * 4]) = *reinterpret_cast<const float4*>(&src[id * 4]);
  }
  __syncthreads();
  const int w = t >> 6, l = t & 63;
  unsigned short* dstb = VT + (size_t)bh * DK * SEQ + p0;
#pragma unroll
  for (int it = 0; it < 4; ++it) {
    int d = w * 32 + (it & 1) * 16 + (l & 15);
    int kc = (it >> 1) * 4 + (l >> 4);
    unsigned short tmp[8];
#pragma unroll
    for (int j = 0; j < 8; ++j) tmp[j] = f2bf(vs[(kc * 8 + j) * DK + d]);
    *reinterpret_cast<uint4*>(&dstb[(size_t)d * SEQ + kc * 8]) =
        *reinterpret_cast<const uint4*>(tmp);
  }
}

// ---------------------------------------------------------------------------
// Fused causal flash attention — 512 thr / 8 waves, one block per (bh, pair).
// Pair {15-pj, pj}: 17 stage-iters of 128 keys for EVERY block (balanced).
// Grid (bh=32, pj=8): lin%8 = bh%8 -> all pair-blocks of a bh share an XCD;
// 4 bh/XCD => K+VT working set ~4MB = L2-resident.
// KVBLK=128 per barrier-pair (2 sub-tiles of 64, no barrier between).
// LDS 112KB: Qs 32 + Ks 32 + Vts 32 + Ps 16.
// ---------------------------------------------------------------------------
struct __align__(16) AttnSmem {
  unsigned short Qs[128 * 128];   // 32KB  [q][dk], swizzled
  unsigned short Ks[128 * 128];   // 32KB  [key][dk], swizzled   (epilogue reuse)
  unsigned short Vts[128 * 128];  // 32KB  [d][key], swizzled
  unsigned short Ps[8 * 16 * 64]; // 16KB  per-wave P [16 q][64 key], swizzled
};

__global__ __launch_bounds__(512, 1)
void attn_fused(const unsigned short* __restrict__ Q,
                const unsigned short* __restrict__ K,
                const unsigned short* __restrict__ VT,
                unsigned short* __restrict__ AO) {
  __shared__ AttnSmem sm;
  const int t = threadIdx.x;          // 0..511
  const int lane = t & 63;
  const int wid = t >> 6;             // 0..7
  const int l16 = lane & 15, lg = lane >> 4;
  const int bh = blockIdx.x;          // 0..31  (lin%8 = bh%8 -> XCD locality)
  const int pj = blockIdx.y;          // 0..7 pair id
  const int b = bh >> 4, h = bh & 15;

  const unsigned short* Kbase = K + (size_t)bh * SEQ * DK;
  const unsigned short* VTbase = VT + (size_t)bh * DK * SEQ;

  for (int half = 0; half < 2; ++half) {
    const int qt = half ? pj : (15 - pj);
    const int q0 = qt * 128;
    const int nst = qt + 1;           // 128-key stage-iters
    const unsigned short* Qbase = Q + ((size_t)bh * SEQ + q0) * DK;

    // stage Q tile [128][128]: 16 chunks/row, swizzle c^(r&7)
#pragma unroll
    for (int s = 0; s < 4; ++s) {
      int id = s * 512 + t;
      int r = id >> 4, c = id & 15;
      uint4 v = *reinterpret_cast<const uint4*>(Qbase + (size_t)r * DK + (c << 3));
      *reinterpret_cast<uint4*>(&sm.Qs[r * 128 + ((c ^ (r & 7)) << 3)]) = v;
    }

    f32x4 accO[8] = {};
    float mrun[4], lrun[4];
#pragma unroll
    for (int r = 0; r < 4; ++r) { mrun[r] = -INFINITY; lrun[r] = 0.f; }

    uint4 pk[4], pv[4];
#pragma unroll
    for (int s = 0; s < 4; ++s) {
      int id = s * 512 + t;
      int rk = id >> 4, ck = id & 15;
      pk[s] = *reinterpret_cast<const uint4*>(Kbase + (size_t)rk * DK + (ck << 3));
      pv[s] = *reinterpret_cast<const uint4*>(VTbase + (size_t)rk * SEQ + (ck << 3));
    }

    for (int kt = 0; kt < nst; ++kt) {
      __syncthreads();
#pragma unroll
      for (int s = 0; s < 4; ++s) {
        int id = s * 512 + t;
        int rk = id >> 4, ck = id & 15;
        int sw = ((ck ^ (rk & 7)) << 3);
        *reinterpret_cast<uint4*>(&sm.Ks[rk * 128 + sw]) = pk[s];
        *reinterpret_cast<uint4*>(&sm.Vts[rk * 128 + sw]) = pv[s];
      }
      __syncthreads();
      if (kt + 1 < nst) {
        const int kn = (kt + 1) * 128;
#pragma unroll
        for (int s = 0; s < 4; ++s) {
          int id = s * 512 + t;
          int rk = id >> 4, ck = id & 15;
          pk[s] = *reinterpret_cast<const uint4*>(Kbase + (size_t)(kn + rk) * DK + (ck << 3));
          pv[s] = *reinterpret_cast<const uint4*>(VTbase + (size_t)rk * SEQ + kn + (ck << 3));
        }
      }

#pragma unroll
      for (int sub = 0; sub < 2; ++sub) {
        const int key0 = kt * 128 + sub * 64;

        // ---- S = Q K^T  (16 q-rows per wave) ----------------------------
        f32x4 sf[4] = {};
        __builtin_amdgcn_s_setprio(1);
#pragma unroll
        for (int ks = 0; ks < 4; ++ks) {
          int ra = wid * 16 + l16;
          bf16x8 aq = *reinterpret_cast<const bf16x8*>(
              &sm.Qs[ra * 128 + (((ks * 4 + lg) ^ (ra & 7)) << 3)]);
#pragma unroll
          for (int nj = 0; nj < 4; ++nj) {
            int rb = sub * 64 + nj * 16 + l16;
            bf16x8 bk = *reinterpret_cast<const bf16x8*>(
                &sm.Ks[rb * 128 + (((ks * 4 + lg) ^ (rb & 7)) << 3)]);
            sf[nj] = __builtin_amdgcn_mfma_f32_16x16x32_bf16(aq, bk, sf[nj], 0, 0, 0);
          }
        }
        __builtin_amdgcn_s_setprio(0);

        // ---- scale + causal mask ----------------------------------------
        const int qwbase = q0 + wid * 16;
        const bool need_mask = (key0 + 63) > qwbase;
#pragma unroll
        for (int nj = 0; nj < 4; ++nj) {
          int kcol = key0 + nj * 16 + l16;
#pragma unroll
          for (int r = 0; r < 4; ++r) {
            float v = sf[nj][r] * ATTN_SCALE;
            if (need_mask) {
              int qrow = qwbase + lg * 4 + r;
              if (kcol > qrow) v = -INFINITY;
            }
            sf[nj][r] = v;
          }
        }

        // ---- online softmax ---------------------------------------------
        float alpha[4];
#pragma unroll
        for (int r = 0; r < 4; ++r) {
          float m0 = fmaxf(fmaxf(sf[0][r], sf[1][r]), fmaxf(sf[2][r], sf[3][r]));
#pragma unroll
          for (int off = 1; off < 16; off <<= 1)
            m0 = fmaxf(m0, __shfl_xor(m0, off, 64));
          float mn = fmaxf(mrun[r], m0);
          alpha[r] = __expf(mrun[r] - mn);   // exp(-inf)=0 on first tile
          mrun[r] = mn;
        }
        float rs[4] = {0.f, 0.f, 0.f, 0.f};
#pragma unroll
        for (int nj = 0; nj < 4; ++nj) {
          int colb = nj * 16 + l16;
          int ch = colb >> 3, cb = colb & 7;
#pragma unroll
          for (int r = 0; r < 4; ++r) {
            float p = __expf(sf[nj][r] - mrun[r]);
            rs[r] += p;
            int prow = lg * 4 + r;
            sm.Ps[wid * 1024 + prow * 64 + ((ch ^ (prow & 7)) << 3) + cb] = f2bf(p);
          }
        }
#pragma unroll
        for (int r = 0; r < 4; ++r) {
          float s0 = rs[r];
#pragma unroll
          for (int off = 1; off < 16; off <<= 1)
            s0 += __shfl_xor(s0, off, 64);
          lrun[r] = lrun[r] * alpha[r] + s0;
        }
#pragma unroll
        for (int dj = 0; dj < 8; ++dj)
#pragma unroll
          for (int r = 0; r < 4; ++r) accO[dj][r] *= alpha[r];

        // ---- PV ---------------------------------------------------------
        __builtin_amdgcn_s_setprio(1);
#pragma unroll
        for (int ks = 0; ks < 2; ++ks) {
          bf16x8 ap = *reinterpret_cast<const bf16x8*>(
              &sm.Ps[wid * 1024 + l16 * 64 + (((ks * 4 + lg) ^ (l16 & 7)) << 3)]);
#pragma unroll
          for (int dj = 0; dj < 8; ++dj) {
            int rv = dj * 16 + l16;
            int c = sub * 8 + ks * 4 + lg;
            bf16x8 bv = *reinterpret_cast<const bf16x8*>(
                &sm.Vts[rv * 128 + ((c ^ (rv & 7)) << 3)]);
            accO[dj] = __builtin_amdgcn_mfma_f32_16x16x32_bf16(ap, bv, accO[dj], 0, 0, 0);
          }
        }
        __builtin_amdgcn_s_setprio(0);
      }
    }

    // ---- epilogue: reuse (dead) Ks as per-wave 16x128 transpose tile ----
    __syncthreads();   // all waves done reading Ks/Vts
    unsigned short* Pw = sm.Ks + wid * 2048;
    float inv[4];
#pragma unroll
    for (int r = 0; r < 4; ++r) inv[r] = 1.0f / lrun[r];
#pragma unroll
    for (int dj = 0; dj < 8; ++dj)
#pragma unroll
      for (int r = 0; r < 4; ++r)
        Pw[(lg * 4 + r) * 128 + dj * 16 + l16] = f2bf(accO[dj][r] * inv[r]);
    // same-wave write->read; compiler inserts lgkmcnt
#pragma unroll
    for (int ps = 0; ps < 4; ++ps) {
      int row = ps * 4 + lg;               // 0..15
      uint4 v = *reinterpret_cast<const uint4*>(&Pw[row * 128 + l16 * 8]);
      int qpos = q0 + wid * 16 + row;
      *reinterpret_cast<uint4*>(
          &AO[((size_t)(b * SEQ + qpos)) * DIM + h * DK + l16 * 8]) = v;
    }
    __syncthreads();   // protect Ks before next half restages
  }
}

// ---------------------------------------------------------------------------
extern "C" void kernel_launch(void* const* d_in, const int* in_sizes, int n_in,
                              void* d_out, int out_size, void* d_ws, size_t ws_size,
                              hipStream_t stream) {
  const float* x  = (const float*)d_in[0];
  const float* wq = (const float*)d_in[1];
  const float* wk = (const float*)d_in[2];
  const float* wv = (const float*)d_in[3];
  const float* wo = (const float*)d_in[4];

  // Outputs are FLOAT32: out [B,S,DIM], K [B,H,S,DK], V [B,H,S,DK].
  float* outF = (float*)d_out;
  float* outK = outF + TSZ;
  float* outV = outF + 2 * TSZ;

  // bf16 Q/K copies live in the (dead until final GEMM) out[0] f32 slot.
  unsigned short* qb = (unsigned short*)outF;
  unsigned short* kb = qb + TSZ;

  // ws (bf16 elems), total 2*TSZ + WSZ = 41.9 MB (proven footprint):
  unsigned short* xb  = (unsigned short*)d_ws;  // converted x; later VT
  unsigned short* aop = xb + TSZ;               // AO (attn output staging)
  unsigned short* wb  = xb + 2 * TSZ;           // jit-converted weight
  unsigned short* vtb = xb;                     // VT over xb (x dead post-QKV)

  dim3 blk(256);
  dim3 ggrid(16, 32);
  const int cvtW = (int)(WSZ / 2048), n8W = (int)(WSZ / 8);

  cvt_f32_bf16<<<dim3((int)(TSZ / 2048)), blk, 0, stream>>>(x, xb, (int)(TSZ / 8));

  cvt_f32_bf16<<<dim3(cvtW), blk, 0, stream>>>(wq, wb, n8W);
  gemm_rope<1><<<ggrid, blk, 0, stream>>>(xb, wb, qb, nullptr);       // Q bf16

  cvt_f32_bf16<<<dim3(cvtW), blk, 0, stream>>>(wk, wb, n8W);
  gemm_rope<2><<<ggrid, blk, 0, stream>>>(xb, wb, kb, outK);          // K f32+bf16

  cvt_f32_bf16<<<dim3(cvtW), blk, 0, stream>>>(wv, wb, n8W);
  gemm_rope<3><<<ggrid, blk, 0, stream>>>(xb, wb, nullptr, outV);     // V f32

  vtrans<<<dim3(32, 32), blk, 0, stream>>>(outV, vtb);                // VT bf16

  attn_fused<<<dim3(32, 8), dim3(512), 0, stream>>>(qb, kb, vtb, aop);

  cvt_f32_bf16<<<dim3(cvtW), blk, 0, stream>>>(wo, wb, n8W);
  gemm_rope<0><<<ggrid, blk, 0, stream>>>(aop, wb, nullptr, outF);    // final f32
}